// Round 18
// baseline (990.435 us; speedup 1.0000x reference)
//
#include <hip/hip_runtime.h>
#include <math.h>

#define NN 100000
#define PADN 100096    // 782*128
#define NBLK128 782
#define HH 512
#define KK 128
#define BETA 100.0f
#define EPSF 1e-8f
#define ITERS 11
#define NSPLIT 128
#define NCHUNK2 (PADN / 128)  // 782
#define PREPB 1024

typedef __attribute__((ext_vector_type(8))) short short8v;
typedef __attribute__((ext_vector_type(4))) float float4v;

typedef const __attribute__((address_space(1))) void* gas_t;
typedef __attribute__((address_space(3))) void* las_t;

__device__ __forceinline__ void gload16(const void* g, void* l) {
  __builtin_amdgcn_global_load_lds((gas_t)g, (las_t)l, 16, 0, 0);
}

__device__ __forceinline__ unsigned short f2bf(float x) {
  unsigned int u = __float_as_uint(x);
  unsigned int r = (u + 0x7fff + ((u >> 16) & 1)) >> 16;
  return (unsigned short)r;
}
__device__ __forceinline__ float bf2f(unsigned short b) {
  return __uint_as_float((unsigned int)b << 16);
}
__device__ __forceinline__ unsigned char f2fp8(float x) {
  return (unsigned char)(__builtin_amdgcn_cvt_pk_fp8_f32(x, x, 0, false) & 0xff);
}
__device__ __forceinline__ float fp82f(unsigned char b) {
  return __builtin_amdgcn_cvt_f32_fp8((unsigned int)b, 0);
}
// convert 8 packed fp8 (uint2) -> float[8] with literal selectors
#define CVT8_FP8(dst, pv)                                      \
  dst[0] = __builtin_amdgcn_cvt_f32_fp8((pv).x, 0);            \
  dst[1] = __builtin_amdgcn_cvt_f32_fp8((pv).x, 1);            \
  dst[2] = __builtin_amdgcn_cvt_f32_fp8((pv).x, 2);            \
  dst[3] = __builtin_amdgcn_cvt_f32_fp8((pv).x, 3);            \
  dst[4] = __builtin_amdgcn_cvt_f32_fp8((pv).y, 0);            \
  dst[5] = __builtin_amdgcn_cvt_f32_fp8((pv).y, 1);            \
  dst[6] = __builtin_amdgcn_cvt_f32_fp8((pv).y, 2);            \
  dst[7] = __builtin_amdgcn_cvt_f32_fp8((pv).y, 3);

__device__ __forceinline__ float wave_reduce_sum(float v) {
#pragma unroll
  for (int off = 32; off > 0; off >>= 1) v += __shfl_xor(v, off);
  return v;
}
__device__ __forceinline__ float softplusf(float x) {
  return fmaxf(x, 0.0f) + log1pf(expf(-fabsf(x)));
}

// ---- fused prep: inv_norm, colpart, posbb (bf16, for transpose), posb8 (fp8, for dist/loss)
__global__ void prep_kernel(const float* __restrict__ pos,
                            float* __restrict__ inv_norm,
                            float* __restrict__ colpart,
                            unsigned short* __restrict__ posbb,
                            unsigned char* __restrict__ posb8) {
  int t = threadIdx.x;
  int w = t >> 6, lane = t & 63;
  int gw = blockIdx.x * 4 + w;
  float cpart[8] = {0, 0, 0, 0, 0, 0, 0, 0};
  for (int row = gw; row < NN; row += PREPB * 4) {
    const float* p = pos + (size_t)row * HH + lane * 8;
    float4 f0 = *(const float4*)p;
    float4 f1 = *(const float4*)(p + 4);
    float v[8] = {f0.x, f0.y, f0.z, f0.w, f1.x, f1.y, f1.z, f1.w};
    float ss = 0.f;
#pragma unroll
    for (int u = 0; u < 8; ++u) {
      ss += v[u] * v[u];
      cpart[u] += v[u];
    }
    ss = wave_reduce_sum(ss);
    float inv = 1.0f / (sqrtf(ss) + EPSF);
    if (lane == 0) inv_norm[row] = inv;
    short8v o;
#pragma unroll
    for (int u = 0; u < 8; ++u) o[u] = (short)f2bf(v[u] * inv);
    *(short8v*)&posbb[(size_t)row * HH + lane * 8] = o;
    int p0 = 0, p1 = 0;
    p0 = __builtin_amdgcn_cvt_pk_fp8_f32(v[0] * inv, v[1] * inv, p0, false);
    p0 = __builtin_amdgcn_cvt_pk_fp8_f32(v[2] * inv, v[3] * inv, p0, true);
    p1 = __builtin_amdgcn_cvt_pk_fp8_f32(v[4] * inv, v[5] * inv, p1, false);
    p1 = __builtin_amdgcn_cvt_pk_fp8_f32(v[6] * inv, v[7] * inv, p1, true);
    int2 pk = {p0, p1};
    *(int2*)&posb8[(size_t)row * HH + lane * 8] = pk;
  }
  {
    int idx = blockIdx.x * 256 + t;
    if (idx < (PADN - NN) * HH / 8) {
      short8v z = (short8v){0, 0, 0, 0, 0, 0, 0, 0};
      *(short8v*)&posbb[(size_t)NN * HH + idx * 8] = z;
    }
    if (idx < (PADN - NN) * HH / 16) {
      int4 z4 = {0, 0, 0, 0};
      *(int4*)&posb8[(size_t)NN * HH + idx * 16] = z4;
    }
  }
  __shared__ float cs[HH];
  cs[t] = 0.f;
  cs[t + 256] = 0.f;
  __syncthreads();
#pragma unroll
  for (int u = 0; u < 8; ++u) atomicAdd(&cs[lane * 8 + u], cpart[u]);
  __syncthreads();
  colpart[(size_t)blockIdx.x * HH + t] = cs[t];
  colpart[(size_t)blockIdx.x * HH + t + 256] = cs[t + 256];
}

// ---- transpose posbb (bf16) -> posbT8 (fp8): LDS tile stays 2B; convert on output
__launch_bounds__(256)
__global__ void transpose_kernel(const unsigned short* __restrict__ posbb,
                                 unsigned char* __restrict__ posbT8) {
  __shared__ unsigned short tile[64][72];
  int t = threadIdx.x;
  int i0 = blockIdx.x * 64, h0 = blockIdx.y * 64;
  int r = t >> 2, cq = (t & 3) * 16;
#pragma unroll
  for (int q = 0; q < 2; ++q) {
    short8v v = *(const short8v*)&posbb[(size_t)(i0 + r) * HH + h0 + cq + q * 8];
#pragma unroll
    for (int e = 0; e < 8; ++e) tile[cq + q * 8 + e][r] = (unsigned short)v[e];
  }
  __syncthreads();
  int h = t >> 2, iq = (t & 3) * 16;
  const unsigned short* src = &tile[h][iq];
  int o[4];
#pragma unroll
  for (int q = 0; q < 4; ++q) {
    int pk = 0;
    pk = __builtin_amdgcn_cvt_pk_fp8_f32(bf2f(src[q * 4 + 0]), bf2f(src[q * 4 + 1]), pk, false);
    pk = __builtin_amdgcn_cvt_pk_fp8_f32(bf2f(src[q * 4 + 2]), bf2f(src[q * 4 + 3]), pk, true);
    o[q] = pk;
  }
  int4 ov = {o[0], o[1], o[2], o[3]};
  *(int4*)&posbT8[(size_t)(h0 + h) * PADN + i0 + iq] = ov;
}

// ---- gs[h] = sigmoid(sum_b colpart[b][h] / N)
__global__ void gs_kernel(const float* __restrict__ colpart, float* __restrict__ gs) {
  int t = threadIdx.x;  // 512
  float s = 0.f;
  for (int b = 0; b < PREPB; ++b) s += colpart[(size_t)b * HH + t];
  float m = s * (1.0f / NN);
  gs[t] = 1.0f / (1.0f + expf(-m));
}

// ---- Ws[j] = sum_h W[j][h]*gs[h]
__global__ void wsum_kernel(const float* __restrict__ W, const float* __restrict__ gs,
                            float* __restrict__ Ws) {
  int w = threadIdx.x >> 6, lane = threadIdx.x & 63;
  int row = blockIdx.x * 4 + w;
  const float* Wr = W + (size_t)row * HH;
  float s = 0.f;
#pragma unroll
  for (int j = 0; j < 8; ++j) s += Wr[lane + 64 * j] * gs[lane + 64 * j];
  s = wave_reduce_sum(s);
  if (lane == 0) Ws[row] = s;
}

// ---- mub8 (fp8) = row / ||row|| from fp32 src. Used once on init.
__global__ void norm_mu_kernel(const float* __restrict__ src, unsigned char* __restrict__ mub8) {
  int k = blockIdx.x, t = threadIdx.x;
  float v0 = src[k * HH + t], v1 = src[k * HH + t + 256];
  float ss = v0 * v0 + v1 * v1;
  ss = wave_reduce_sum(ss);
  __shared__ float red[4];
  if ((t & 63) == 0) red[t >> 6] = ss;
  __syncthreads();
  float inv = 1.0f / sqrtf(red[0] + red[1] + red[2] + red[3]);
  mub8[k * HH + t] = f2fp8(v0 * inv);
  mub8[k * HH + t + 256] = f2fp8(v1 * inv);
}

// ---- FP8 MFMA dist + fused softmax. BM=128, chunk=64 k (64B rows), 8 chunks, T4 vmcnt.
__launch_bounds__(256, 4)
__global__ void dist_mfma(const unsigned char* __restrict__ posb8,
                          const unsigned char* __restrict__ mub8,
                          unsigned char* __restrict__ rbf8,
                          unsigned char* __restrict__ rbfT8,
                          float* __restrict__ crblk,
                          int write_rbf) {
  __shared__ __align__(16) unsigned char smem[32768];  // As[2][8192] | Bs[2][8192]
  unsigned char* As0 = smem;
  unsigned char* Bs0 = smem + 16384;
  unsigned char* rT8 = smem;  // [128 c][144] epilogue alias (18.4KB)
  __shared__ float redM[2][128];
  __shared__ float redS[2][128];
  __shared__ float crS[2][128];

  int t = threadIdx.x;
  int w = t >> 6, l = t & 63;
  int wr = w >> 1, wc = w & 1;
  int i0 = blockIdx.x * 128;

  float4v acc[4][4];
#pragma unroll
  for (int mi = 0; mi < 4; ++mi)
#pragma unroll
    for (int ni = 0; ni < 4; ++ni) acc[mi][ni] = (float4v){0.f, 0.f, 0.f, 0.f};

  int rsub = l >> 2;                          // staged row within 16-row v-group
  int sslot = ((l & 3) ^ (rsub & 3)) << 4;    // swizzled source byte slot

  auto stage = [&](int buf, int ch) {
    int h0 = ch * 64;
#pragma unroll
    for (int j = 0; j < 2; ++j) {
      int v = w * 2 + j;        // 0..7
      int row = v * 16 + rsub;  // 0..127
      gload16(posb8 + (size_t)(i0 + row) * HH + h0 + sslot, As0 + buf * 8192 + v * 1024);
      gload16(mub8 + (size_t)row * HH + h0 + sslot, Bs0 + buf * 8192 + v * 1024);
    }
  };

  stage(0, 0);  // 4 loads in flight
  int cur = 0;
  int g = l >> 4;
  int half8 = (g & 1) * 8;
  for (int ch = 0; ch < 8; ++ch) {
    if (ch < 7) {
      stage(cur ^ 1, ch + 1);  // 8 outstanding
      asm volatile("s_waitcnt vmcnt(4)" ::: "memory");
    } else {
      asm volatile("s_waitcnt vmcnt(0)" ::: "memory");
    }
    __builtin_amdgcn_s_barrier();
    __builtin_amdgcn_sched_barrier(0);
    const char* ab = (const char*)(As0 + cur * 8192);
    const char* bb = (const char*)(Bs0 + cur * 8192);
#pragma unroll
    for (int ks = 0; ks < 2; ++ks) {
      long af[4], bfr[4];
      int slot16 = ks * 2 + (g >> 1);
      int soff = ((slot16 ^ (l & 3)) << 4) + half8;
#pragma unroll
      for (int mi = 0; mi < 4; ++mi) {
        int row = wr * 64 + mi * 16 + (l & 15);
        af[mi] = *(const long*)(ab + row * 64 + soff);
      }
#pragma unroll
      for (int ni = 0; ni < 4; ++ni) {
        int row = wc * 64 + ni * 16 + (l & 15);
        bfr[ni] = *(const long*)(bb + row * 64 + soff);
      }
#pragma unroll
      for (int mi = 0; mi < 4; ++mi)
#pragma unroll
        for (int ni = 0; ni < 4; ++ni)
          acc[mi][ni] = __builtin_amdgcn_mfma_f32_16x16x32_fp8_fp8(af[mi], bfr[ni], acc[mi][ni], 0, 0, 0);
    }
    __builtin_amdgcn_sched_barrier(0);
    __builtin_amdgcn_s_barrier();
    __builtin_amdgcn_sched_barrier(0);
    cur ^= 1;
  }

  // ---- softmax epilogue. row(local) = wr*64+mi*16+(l>>4)*4+j, col = wc*64+ni*16+(l&15)
  float wmax[4][4];
#pragma unroll
  for (int mi = 0; mi < 4; ++mi)
#pragma unroll
    for (int j = 0; j < 4; ++j) {
      float m = fmaxf(fmaxf(acc[mi][0][j], acc[mi][1][j]), fmaxf(acc[mi][2][j], acc[mi][3][j])) * BETA;
      m = fmaxf(m, __shfl_xor(m, 1));
      m = fmaxf(m, __shfl_xor(m, 2));
      m = fmaxf(m, __shfl_xor(m, 4));
      m = fmaxf(m, __shfl_xor(m, 8));
      wmax[mi][j] = m;
    }
  if ((l & 15) == 0) {
#pragma unroll
    for (int mi = 0; mi < 4; ++mi)
#pragma unroll
      for (int j = 0; j < 4; ++j)
        redM[wc][wr * 64 + mi * 16 + (l >> 4) * 4 + j] = wmax[mi][j];
  }
  __syncthreads();
  float fm[4][4];
#pragma unroll
  for (int mi = 0; mi < 4; ++mi)
#pragma unroll
    for (int j = 0; j < 4; ++j) {
      int row = wr * 64 + mi * 16 + (l >> 4) * 4 + j;
      fm[mi][j] = fmaxf(redM[0][row], redM[1][row]);
    }
#pragma unroll
  for (int mi = 0; mi < 4; ++mi)
#pragma unroll
    for (int j = 0; j < 4; ++j) {
      float s = 0.f;
#pragma unroll
      for (int ni = 0; ni < 4; ++ni) {
        float e = __expf(acc[mi][ni][j] * BETA - fm[mi][j]);
        acc[mi][ni][j] = e;
        s += e;
      }
      s += __shfl_xor(s, 1);
      s += __shfl_xor(s, 2);
      s += __shfl_xor(s, 4);
      s += __shfl_xor(s, 8);
      wmax[mi][j] = s;  // reuse
    }
  if ((l & 15) == 0) {
#pragma unroll
    for (int mi = 0; mi < 4; ++mi)
#pragma unroll
      for (int j = 0; j < 4; ++j)
        redS[wc][wr * 64 + mi * 16 + (l >> 4) * 4 + j] = wmax[mi][j];
  }
  __syncthreads();

  float cpart[4] = {0.f, 0.f, 0.f, 0.f};
#pragma unroll
  for (int mi = 0; mi < 4; ++mi)
#pragma unroll
    for (int j = 0; j < 4; ++j) {
      int row = wr * 64 + mi * 16 + (l >> 4) * 4 + j;
      float invs = 1.0f / (redS[0][row] + redS[1][row]);
      bool valid = (i0 + row) < NN;
#pragma unroll
      for (int ni = 0; ni < 4; ++ni) {
        unsigned char q8 = f2fp8(acc[mi][ni][j] * invs);
        if (valid) cpart[ni] += fp82f(q8);  // consistent with quantized numerator
        rT8[(wc * 64 + ni * 16 + (l & 15)) * 144 + row] = q8;
      }
    }
#pragma unroll
  for (int ni = 0; ni < 4; ++ni) {
    float c = cpart[ni];
    c += __shfl_xor(c, 16);
    c += __shfl_xor(c, 32);
    if (l < 16) crS[wr][wc * 64 + ni * 16 + l] = c;
  }
  __syncthreads();
  if (t < 128) crblk[(size_t)blockIdx.x * KK + t] = crS[0][t] + crS[1][t];

  {
    int c = t >> 1, half = t & 1;
    const unsigned char* src = &rT8[c * 144 + half * 64];
    unsigned char* dst = &rbfT8[(size_t)c * PADN + i0 + half * 64];
#pragma unroll
    for (int q = 0; q < 4; ++q)
      *(short8v*)(dst + q * 16) = *(const short8v*)(src + q * 16);
  }
  if (write_rbf) {
    int i = t >> 1, chalf = t & 1;
#pragma unroll
    for (int q = 0; q < 8; ++q) {
      unsigned int lo = 0, hi = 0;
#pragma unroll
      for (int e = 0; e < 4; ++e)
        lo |= ((unsigned int)rT8[(chalf * 64 + q * 8 + e) * 144 + i]) << (8 * e);
#pragma unroll
      for (int e = 0; e < 4; ++e)
        hi |= ((unsigned int)rT8[(chalf * 64 + q * 8 + 4 + e) * 144 + i]) << (8 * e);
      uint2 pk = {lo, hi};
      *(uint2*)&rbf8[(size_t)(i0 + i) * KK + chalf * 64 + q * 8] = pk;
    }
  }
}

// ---- FP8 MFMA mu update. chunk=128 i (128B rows), T4 vmcnt. part now fp8.
__launch_bounds__(256, 2)
__global__ void muup_mfma(const unsigned char* __restrict__ rbfT8,
                          const unsigned char* __restrict__ posbT8,
                          unsigned char* __restrict__ part8) {
  __shared__ __align__(16) unsigned char smem[65536];  // As[2][16384] | Bs[2][16384]
  unsigned char* As0 = smem;
  unsigned char* Bs0 = smem + 32768;
  int t = threadIdx.x;
  int w = t >> 6, l = t & 63;
  int wr = w >> 1, wc = w & 1;
  int ht = blockIdx.x, s = blockIdx.y;

  float4v acc[4][4];
#pragma unroll
  for (int mi = 0; mi < 4; ++mi)
#pragma unroll
    for (int ni = 0; ni < 4; ++ni) acc[mi][ni] = (float4v){0.f, 0.f, 0.f, 0.f};

  int rsub = l >> 3;                          // 0..7
  int sslot = ((l & 7) ^ rsub) << 4;          // swizzled source byte slot

  auto stage = [&](int buf, int ch) {
    size_t ib = (size_t)ch * 128;
#pragma unroll
    for (int j = 0; j < 4; ++j) {
      int v = w * 4 + j;       // 0..15
      int row = v * 8 + rsub;  // 0..127
      gload16(rbfT8 + (size_t)row * PADN + ib + sslot, As0 + buf * 16384 + v * 1024);
      gload16(posbT8 + (size_t)(ht * 128 + row) * PADN + ib + sslot, Bs0 + buf * 16384 + v * 1024);
    }
  };

  int ch = s;
  stage(0, ch);  // 8 loads in flight
  int cur = 0;
  int g = l >> 4;
  int half8 = (g & 1) * 8;
  for (; ch < NCHUNK2; ch += NSPLIT) {
    int nxt = ch + NSPLIT;
    if (nxt < NCHUNK2) {
      stage(cur ^ 1, nxt);
      asm volatile("s_waitcnt vmcnt(8)" ::: "memory");
    } else {
      asm volatile("s_waitcnt vmcnt(0)" ::: "memory");
    }
    __builtin_amdgcn_s_barrier();
    __builtin_amdgcn_sched_barrier(0);
    const char* ab = (const char*)(As0 + cur * 16384);
    const char* bb = (const char*)(Bs0 + cur * 16384);
#pragma unroll
    for (int ks = 0; ks < 4; ++ks) {
      long af[4], bfr[4];
      int slot16 = ks * 2 + (g >> 1);
#pragma unroll
      for (int mi = 0; mi < 4; ++mi) {
        int row = wr * 64 + mi * 16 + (l & 15);
        af[mi] = *(const long*)(ab + row * 128 + ((slot16 ^ (l & 7)) << 4) + half8);
      }
#pragma unroll
      for (int ni = 0; ni < 4; ++ni) {
        int row = wc * 64 + ni * 16 + (l & 15);
        bfr[ni] = *(const long*)(bb + row * 128 + ((slot16 ^ (l & 7)) << 4) + half8);
      }
#pragma unroll
      for (int mi = 0; mi < 4; ++mi)
#pragma unroll
        for (int ni = 0; ni < 4; ++ni)
          acc[mi][ni] = __builtin_amdgcn_mfma_f32_16x16x32_fp8_fp8(af[mi], bfr[ni], acc[mi][ni], 0, 0, 0);
    }
    __builtin_amdgcn_sched_barrier(0);
    __builtin_amdgcn_s_barrier();
    __builtin_amdgcn_sched_barrier(0);
    cur ^= 1;
  }
#pragma unroll
  for (int mi = 0; mi < 4; ++mi)
#pragma unroll
    for (int ni = 0; ni < 4; ++ni)
#pragma unroll
      for (int j = 0; j < 4; ++j) {
        int c = wr * 64 + mi * 16 + (l >> 4) * 4 + j;
        int hh = wc * 64 + ni * 16 + (l & 15);
        part8[((size_t)s * KK + c) * HH + ht * 128 + hh] = f2fp8(acc[mi][ni][j]);
      }
}

// ---- fused fin+norm: cr = sum_b crblk; v = (sum_s part8)/cr; mub8 = fp8 normalize(v); mubT8 (last)
__global__ void finorm_kernel(const unsigned char* __restrict__ part8,
                              const float* __restrict__ crblk,
                              unsigned char* __restrict__ mub8,
                              unsigned char* __restrict__ mubT8, int write_mubT) {
  int c = blockIdx.x, t = threadIdx.x;
  __shared__ float credL[4];
  float crp = 0.f;
  for (int b = t; b < NBLK128; b += 256) crp += crblk[(size_t)b * KK + c];
  crp = wave_reduce_sum(crp);
  if ((t & 63) == 0) credL[t >> 6] = crp;
  __syncthreads();
  float cr = credL[0] + credL[1] + credL[2] + credL[3];
  float inv = 1.0f / cr;
  float s0 = 0.f, s1 = 0.f;
  const unsigned char* pb = part8 + (size_t)c * HH;
#pragma unroll 4
  for (int s2 = 0; s2 < NSPLIT; ++s2) {
    s0 += fp82f(pb[(size_t)s2 * KK * HH + t]);
    s1 += fp82f(pb[(size_t)s2 * KK * HH + t + 256]);
  }
  float v0 = s0 * inv, v1 = s1 * inv;
  if (write_mubT) {
    mubT8[(size_t)t * KK + c] = f2fp8(v0);
    mubT8[(size_t)(t + 256) * KK + c] = f2fp8(v1);
  }
  float ss = v0 * v0 + v1 * v1;
  ss = wave_reduce_sum(ss);
  __shared__ float red[4];
  if ((t & 63) == 0) red[t >> 6] = ss;
  __syncthreads();
  float rn = 1.0f / sqrtf(red[0] + red[1] + red[2] + red[3]);
  mub8[c * HH + t] = f2fp8(v0 * rn);
  mub8[c * HH + t + 256] = f2fp8(v1 * rn);
}

// ---- cs8[i][h] = fp8(sigmoid(sum_k r[i][k]*mu[h][k])). Tile 128i x 128h, K=128 one-shot.
__launch_bounds__(256, 4)
__global__ void cs_mfma(const unsigned char* __restrict__ rbf8,
                        const unsigned char* __restrict__ mubT8,
                        unsigned char* __restrict__ cs8) {
  __shared__ __align__(16) unsigned char smem[32768];  // As 16KB | Bs 16KB; ct alias 18.4KB
  unsigned char* As = smem;
  unsigned char* Bs = smem + 16384;
  unsigned char* ct = smem;  // [128 i][144] epilogue alias
  int t = threadIdx.x;
  int w = t >> 6, l = t & 63;
  int wr = w >> 1, wc = w & 1;
  int i0 = blockIdx.x * 128;
  int h0 = blockIdx.y * 128;

  int rsub = l >> 3;
  int sslot = ((l & 7) ^ rsub) << 4;
  {
    const unsigned char* ga = rbf8 + (size_t)i0 * KK;
    const unsigned char* gb = mubT8 + (size_t)h0 * KK;
#pragma unroll
    for (int j = 0; j < 4; ++j) {
      int v = w * 4 + j;
      int row = v * 8 + rsub;
      gload16(ga + (size_t)row * KK + sslot, As + v * 1024);
      gload16(gb + (size_t)row * KK + sslot, Bs + v * 1024);
    }
  }
  __syncthreads();  // full waitcnt drain + barrier

  float4v acc[4][4];
#pragma unroll
  for (int mi = 0; mi < 4; ++mi)
#pragma unroll
    for (int ni = 0; ni < 4; ++ni) acc[mi][ni] = (float4v){0.f, 0.f, 0.f, 0.f};

  int g = l >> 4;
  int half8 = (g & 1) * 8;
#pragma unroll
  for (int ks = 0; ks < 4; ++ks) {
    long af[4], bfr[4];
    int slot16 = ks * 2 + (g >> 1);
    int soff = ((slot16 ^ (l & 7)) << 4) + half8;
#pragma unroll
    for (int mi = 0; mi < 4; ++mi) {
      int row = wr * 64 + mi * 16 + (l & 15);  // i row
      af[mi] = *(const long*)((const char*)As + row * 128 + soff);
    }
#pragma unroll
    for (int ni = 0; ni < 4; ++ni) {
      int row = wc * 64 + ni * 16 + (l & 15);  // h row
      bfr[ni] = *(const long*)((const char*)Bs + row * 128 + soff);
    }
#pragma unroll
    for (int mi = 0; mi < 4; ++mi)
#pragma unroll
      for (int ni = 0; ni < 4; ++ni)
        acc[mi][ni] = __builtin_amdgcn_mfma_f32_16x16x32_fp8_fp8(af[mi], bfr[ni], acc[mi][ni], 0, 0, 0);
  }
  __syncthreads();  // MFMA LDS reads done before ct overwrites As/Bs

  // sigmoid -> ct [i][144]
#pragma unroll
  for (int mi = 0; mi < 4; ++mi)
#pragma unroll
    for (int ni = 0; ni < 4; ++ni)
#pragma unroll
      for (int j = 0; j < 4; ++j) {
        int row = wr * 64 + mi * 16 + (l >> 4) * 4 + j;
        int col = wc * 64 + ni * 16 + (l & 15);
        ct[row * 144 + col] = f2fp8(1.0f / (1.0f + __expf(-acc[mi][ni][j])));
      }
  __syncthreads();

  {
    int r2 = t >> 1, half = t & 1;
    const unsigned char* src = ct + r2 * 144 + half * 64;
    unsigned char* dst = cs8 + (size_t)(i0 + r2) * HH + h0 + half * 64;
#pragma unroll
    for (int q = 0; q < 4; ++q)
      *(short8v*)(dst + q * 16) = *(const short8v*)(src + q * 16);
  }
}

// ---- pure streaming loss: one wave per row; reads cs8/posb8 (fp8) + neg (fp32); no barriers.
__launch_bounds__(256)
__global__ void loss_stream(const unsigned char* __restrict__ cs8,
                            const unsigned char* __restrict__ posb8,
                            const float* __restrict__ neg,
                            const float* __restrict__ inv_norm,
                            const float* __restrict__ Wsv,
                            float* __restrict__ loss_accum) {
  __shared__ float WsS[HH];
  __shared__ float bred[4];
  int t = threadIdx.x;
  WsS[t] = Wsv[t];
  WsS[t + 256] = Wsv[t + 256];
  __syncthreads();
  int w = t >> 6, l = t & 63;
  float total = 0.f;
  for (int row = blockIdx.x * 4 + w; row < NN; row += 2048 * 4) {
    const unsigned char* cr = cs8 + (size_t)row * HH + l * 8;
    const unsigned char* pr = posb8 + (size_t)row * HH + l * 8;
    const float* nr = neg + (size_t)row * HH + l * 8;
    uint2 c8 = *(const uint2*)cr;
    uint2 p8 = *(const uint2*)pr;
    float4 n0 = *(const float4*)nr;
    float4 n1 = *(const float4*)(nr + 4);
    float sf[8], pf[8];
    CVT8_FP8(sf, c8)
    CVT8_FP8(pf, p8)
    float pc = 0.f, nc = 0.f, pg = 0.f, ng = 0.f;
#pragma unroll
    for (int u = 0; u < 8; ++u) {
      float nv = (u < 4) ? (&n0.x)[u] : (&n1.x)[u - 4];
      float wv = WsS[l * 8 + u];
      pc = fmaf(sf[u], pf[u], pc);
      nc = fmaf(sf[u], nv, nc);
      pg = fmaf(wv, pf[u], pg);
      ng = fmaf(wv, nv, ng);
    }
    pc = wave_reduce_sum(pc);
    nc = wave_reduce_sum(nc);
    pg = wave_reduce_sum(pg);
    ng = wave_reduce_sum(ng);
    if (l == 0) {
      float nrm = 1.0f / inv_norm[row];  // ||pos||+eps
      total += 0.5f * (softplusf(-pg * nrm) + softplusf(ng)) +
               0.5f * (softplusf(-pc * nrm) + softplusf(nc));
    }
  }
  if (l == 0) bred[w] = total;
  __syncthreads();
  if (t == 0) atomicAdd(loss_accum, bred[0] + bred[1] + bred[2] + bred[3]);
}

__global__ void out_kernel(const float* __restrict__ loss_accum, float* __restrict__ out) {
  out[0] = loss_accum[0] * (1.0f / NN);
}

extern "C" void kernel_launch(void* const* d_in, const int* in_sizes, int n_in,
                              void* d_out, int out_size, void* d_ws, size_t ws_size,
                              hipStream_t stream) {
  const float* pos = (const float*)d_in[0];
  const float* neg = (const float*)d_in[1];
  const float* init = (const float*)d_in[2];
  const float* W = (const float*)d_in[3];
  float* out = (float*)d_out;

  char* ws = (char*)d_ws;
  size_t off = 0;
  auto alloc = [&](size_t bytes) {
    void* p = ws + off;
    off = (off + bytes + 255) & ~(size_t)255;
    return p;
  };
  unsigned char* posb8 = (unsigned char*)alloc((size_t)PADN * HH);        // 51.2 MB
  unsigned short* posbb = (unsigned short*)alloc((size_t)PADN * HH * 2);  // 102.5 MB
  unsigned char* posbT8 = (unsigned char*)alloc((size_t)HH * PADN);       // 51.2 MB
  unsigned char* rbf8 = (unsigned char*)alloc((size_t)PADN * KK);         // 12.8 MB
  unsigned char* rbfT8 = (unsigned char*)alloc((size_t)KK * PADN);        // 12.8 MB
  unsigned char* cs8 = (unsigned char*)alloc((size_t)PADN * HH);          // 51.2 MB
  unsigned char* part8 = (unsigned char*)alloc((size_t)NSPLIT * KK * HH); // 8.4 MB
  float* colpart = (float*)alloc((size_t)PREPB * HH * 4);                 // 2 MB
  float* crblk = (float*)alloc((size_t)NBLK128 * KK * 4);                 // 400 KB
  float* inv_norm = (float*)alloc((size_t)NN * 4);
  unsigned char* mub8 = (unsigned char*)alloc((size_t)KK * HH);
  unsigned char* mubT8 = (unsigned char*)alloc((size_t)KK * HH);
  float* gs = (float*)alloc(HH * 4);
  float* Ws = (float*)alloc(HH * 4);
  float* loss_accum = (float*)alloc(16);

  hipMemsetAsync(loss_accum, 0, sizeof(float), stream);

  prep_kernel<<<PREPB, 256, 0, stream>>>(pos, inv_norm, colpart, posbb, posb8);
  transpose_kernel<<<dim3(PADN / 64, HH / 64), 256, 0, stream>>>(posbb, posbT8);
  gs_kernel<<<1, 512, 0, stream>>>(colpart, gs);
  wsum_kernel<<<128, 256, 0, stream>>>(W, gs, Ws);

  norm_mu_kernel<<<KK, 256, 0, stream>>>(init, mub8);
  for (int it = 0; it < ITERS; ++it) {
    dist_mfma<<<NBLK128, 256, 0, stream>>>(posb8, mub8, rbf8, rbfT8, crblk, it == ITERS - 1 ? 1 : 0);
    muup_mfma<<<dim3(4, NSPLIT), 256, 0, stream>>>(rbfT8, posbT8, part8);
    finorm_kernel<<<KK, 256, 0, stream>>>(part8, crblk, mub8, mubT8, it == ITERS - 1 ? 1 : 0);
  }

  cs_mfma<<<dim3(NBLK128, 4), 256, 0, stream>>>(rbf8, mubT8, cs8);
  loss_stream<<<2048, 256, 0, stream>>>(cs8, posb8, neg, inv_norm, Ws, loss_accum);
  out_kernel<<<1, 1, 0, stream>>>(loss_accum, out);
}

// Round 19
// 944.833 us; speedup vs baseline: 1.0483x; 1.0483x over previous
//
#include <hip/hip_runtime.h>
#include <math.h>

#define NN 100000
#define PADN 100096    // 782*128
#define NBLK128 782
#define HH 512
#define KK 128
#define BETA 100.0f
#define EPSF 1e-8f
#define ITERS 11
#define NSPLIT 128
#define NCHUNK2 (PADN / 128)  // 782
#define PREPB 1024

typedef __attribute__((ext_vector_type(8))) short short8v;
typedef __attribute__((ext_vector_type(4))) float float4v;

typedef const __attribute__((address_space(1))) void* gas_t;
typedef __attribute__((address_space(3))) void* las_t;

__device__ __forceinline__ void gload16(const void* g, void* l) {
  __builtin_amdgcn_global_load_lds((gas_t)g, (las_t)l, 16, 0, 0);
}

__device__ __forceinline__ unsigned short f2bf(float x) {
  unsigned int u = __float_as_uint(x);
  unsigned int r = (u + 0x7fff + ((u >> 16) & 1)) >> 16;
  return (unsigned short)r;
}
__device__ __forceinline__ float bf2f(unsigned short b) {
  return __uint_as_float((unsigned int)b << 16);
}
__device__ __forceinline__ unsigned char f2fp8(float x) {
  return (unsigned char)(__builtin_amdgcn_cvt_pk_fp8_f32(x, x, 0, false) & 0xff);
}
__device__ __forceinline__ float fp82f(unsigned char b) {
  return __builtin_amdgcn_cvt_f32_fp8((unsigned int)b, 0);
}
// convert 8 packed fp8 (uint2) -> float[8] with literal selectors
#define CVT8_FP8(dst, pv)                                      \
  dst[0] = __builtin_amdgcn_cvt_f32_fp8((pv).x, 0);            \
  dst[1] = __builtin_amdgcn_cvt_f32_fp8((pv).x, 1);            \
  dst[2] = __builtin_amdgcn_cvt_f32_fp8((pv).x, 2);            \
  dst[3] = __builtin_amdgcn_cvt_f32_fp8((pv).x, 3);            \
  dst[4] = __builtin_amdgcn_cvt_f32_fp8((pv).y, 0);            \
  dst[5] = __builtin_amdgcn_cvt_f32_fp8((pv).y, 1);            \
  dst[6] = __builtin_amdgcn_cvt_f32_fp8((pv).y, 2);            \
  dst[7] = __builtin_amdgcn_cvt_f32_fp8((pv).y, 3);

__device__ __forceinline__ float wave_reduce_sum(float v) {
#pragma unroll
  for (int off = 32; off > 0; off >>= 1) v += __shfl_xor(v, off);
  return v;
}
__device__ __forceinline__ float softplusf(float x) {
  return fmaxf(x, 0.0f) + log1pf(expf(-fabsf(x)));
}

// ---- fused prep: inv_norm, colpart, posbb (bf16, for transpose), posb8 (fp8, for dist/loss)
__global__ void prep_kernel(const float* __restrict__ pos,
                            float* __restrict__ inv_norm,
                            float* __restrict__ colpart,
                            unsigned short* __restrict__ posbb,
                            unsigned char* __restrict__ posb8) {
  int t = threadIdx.x;
  int w = t >> 6, lane = t & 63;
  int gw = blockIdx.x * 4 + w;
  float cpart[8] = {0, 0, 0, 0, 0, 0, 0, 0};
  for (int row = gw; row < NN; row += PREPB * 4) {
    const float* p = pos + (size_t)row * HH + lane * 8;
    float4 f0 = *(const float4*)p;
    float4 f1 = *(const float4*)(p + 4);
    float v[8] = {f0.x, f0.y, f0.z, f0.w, f1.x, f1.y, f1.z, f1.w};
    float ss = 0.f;
#pragma unroll
    for (int u = 0; u < 8; ++u) {
      ss += v[u] * v[u];
      cpart[u] += v[u];
    }
    ss = wave_reduce_sum(ss);
    float inv = 1.0f / (sqrtf(ss) + EPSF);
    if (lane == 0) inv_norm[row] = inv;
    short8v o;
#pragma unroll
    for (int u = 0; u < 8; ++u) o[u] = (short)f2bf(v[u] * inv);
    *(short8v*)&posbb[(size_t)row * HH + lane * 8] = o;
    int p0 = 0, p1 = 0;
    p0 = __builtin_amdgcn_cvt_pk_fp8_f32(v[0] * inv, v[1] * inv, p0, false);
    p0 = __builtin_amdgcn_cvt_pk_fp8_f32(v[2] * inv, v[3] * inv, p0, true);
    p1 = __builtin_amdgcn_cvt_pk_fp8_f32(v[4] * inv, v[5] * inv, p1, false);
    p1 = __builtin_amdgcn_cvt_pk_fp8_f32(v[6] * inv, v[7] * inv, p1, true);
    int2 pk = {p0, p1};
    *(int2*)&posb8[(size_t)row * HH + lane * 8] = pk;
  }
  {
    int idx = blockIdx.x * 256 + t;
    if (idx < (PADN - NN) * HH / 8) {
      short8v z = (short8v){0, 0, 0, 0, 0, 0, 0, 0};
      *(short8v*)&posbb[(size_t)NN * HH + idx * 8] = z;
    }
    if (idx < (PADN - NN) * HH / 16) {
      int4 z4 = {0, 0, 0, 0};
      *(int4*)&posb8[(size_t)NN * HH + idx * 16] = z4;
    }
  }
  __shared__ float cs[HH];
  cs[t] = 0.f;
  cs[t + 256] = 0.f;
  __syncthreads();
#pragma unroll
  for (int u = 0; u < 8; ++u) atomicAdd(&cs[lane * 8 + u], cpart[u]);
  __syncthreads();
  colpart[(size_t)blockIdx.x * HH + t] = cs[t];
  colpart[(size_t)blockIdx.x * HH + t + 256] = cs[t + 256];
}

// ---- transpose posbb (bf16) -> posbT8 (fp8): LDS tile stays 2B; convert on output
__launch_bounds__(256)
__global__ void transpose_kernel(const unsigned short* __restrict__ posbb,
                                 unsigned char* __restrict__ posbT8) {
  __shared__ unsigned short tile[64][72];
  int t = threadIdx.x;
  int i0 = blockIdx.x * 64, h0 = blockIdx.y * 64;
  int r = t >> 2, cq = (t & 3) * 16;
#pragma unroll
  for (int q = 0; q < 2; ++q) {
    short8v v = *(const short8v*)&posbb[(size_t)(i0 + r) * HH + h0 + cq + q * 8];
#pragma unroll
    for (int e = 0; e < 8; ++e) tile[cq + q * 8 + e][r] = (unsigned short)v[e];
  }
  __syncthreads();
  int h = t >> 2, iq = (t & 3) * 16;
  const unsigned short* src = &tile[h][iq];
  int o[4];
#pragma unroll
  for (int q = 0; q < 4; ++q) {
    int pk = 0;
    pk = __builtin_amdgcn_cvt_pk_fp8_f32(bf2f(src[q * 4 + 0]), bf2f(src[q * 4 + 1]), pk, false);
    pk = __builtin_amdgcn_cvt_pk_fp8_f32(bf2f(src[q * 4 + 2]), bf2f(src[q * 4 + 3]), pk, true);
    o[q] = pk;
  }
  int4 ov = {o[0], o[1], o[2], o[3]};
  *(int4*)&posbT8[(size_t)(h0 + h) * PADN + i0 + iq] = ov;
}

// ---- gs[h] = sigmoid(sum_b colpart[b][h] / N)
__global__ void gs_kernel(const float* __restrict__ colpart, float* __restrict__ gs) {
  int t = threadIdx.x;  // 512
  float s = 0.f;
  for (int b = 0; b < PREPB; ++b) s += colpart[(size_t)b * HH + t];
  float m = s * (1.0f / NN);
  gs[t] = 1.0f / (1.0f + expf(-m));
}

// ---- Ws[j] = sum_h W[j][h]*gs[h]
__global__ void wsum_kernel(const float* __restrict__ W, const float* __restrict__ gs,
                            float* __restrict__ Ws) {
  int w = threadIdx.x >> 6, lane = threadIdx.x & 63;
  int row = blockIdx.x * 4 + w;
  const float* Wr = W + (size_t)row * HH;
  float s = 0.f;
#pragma unroll
  for (int j = 0; j < 8; ++j) s += Wr[lane + 64 * j] * gs[lane + 64 * j];
  s = wave_reduce_sum(s);
  if (lane == 0) Ws[row] = s;
}

// ---- mub8 (fp8) = row / ||row|| from fp32 src. Used once on init.
__global__ void norm_mu_kernel(const float* __restrict__ src, unsigned char* __restrict__ mub8) {
  int k = blockIdx.x, t = threadIdx.x;
  float v0 = src[k * HH + t], v1 = src[k * HH + t + 256];
  float ss = v0 * v0 + v1 * v1;
  ss = wave_reduce_sum(ss);
  __shared__ float red[4];
  if ((t & 63) == 0) red[t >> 6] = ss;
  __syncthreads();
  float inv = 1.0f / sqrtf(red[0] + red[1] + red[2] + red[3]);
  mub8[k * HH + t] = f2fp8(v0 * inv);
  mub8[k * HH + t + 256] = f2fp8(v1 * inv);
}

// ---- FP8 MFMA dist + fused softmax. BM=128, chunk=64 k (64B rows), 8 chunks, T4 vmcnt.
__launch_bounds__(256, 4)
__global__ void dist_mfma(const unsigned char* __restrict__ posb8,
                          const unsigned char* __restrict__ mub8,
                          unsigned char* __restrict__ rbf8,
                          unsigned char* __restrict__ rbfT8,
                          float* __restrict__ crblk,
                          int write_rbf) {
  __shared__ __align__(16) unsigned char smem[32768];  // As[2][8192] | Bs[2][8192]
  unsigned char* As0 = smem;
  unsigned char* Bs0 = smem + 16384;
  unsigned char* rT8 = smem;  // [128 c][144] epilogue alias (18.4KB)
  __shared__ float redM[2][128];
  __shared__ float redS[2][128];
  __shared__ float crS[2][128];

  int t = threadIdx.x;
  int w = t >> 6, l = t & 63;
  int wr = w >> 1, wc = w & 1;
  int i0 = blockIdx.x * 128;

  float4v acc[4][4];
#pragma unroll
  for (int mi = 0; mi < 4; ++mi)
#pragma unroll
    for (int ni = 0; ni < 4; ++ni) acc[mi][ni] = (float4v){0.f, 0.f, 0.f, 0.f};

  int rsub = l >> 2;                          // staged row within 16-row v-group
  int sslot = ((l & 3) ^ (rsub & 3)) << 4;    // swizzled source byte slot

  auto stage = [&](int buf, int ch) {
    int h0 = ch * 64;
#pragma unroll
    for (int j = 0; j < 2; ++j) {
      int v = w * 2 + j;        // 0..7
      int row = v * 16 + rsub;  // 0..127
      gload16(posb8 + (size_t)(i0 + row) * HH + h0 + sslot, As0 + buf * 8192 + v * 1024);
      gload16(mub8 + (size_t)row * HH + h0 + sslot, Bs0 + buf * 8192 + v * 1024);
    }
  };

  stage(0, 0);  // 4 loads in flight
  int cur = 0;
  int g = l >> 4;
  int half8 = (g & 1) * 8;
  for (int ch = 0; ch < 8; ++ch) {
    if (ch < 7) {
      stage(cur ^ 1, ch + 1);  // 8 outstanding
      asm volatile("s_waitcnt vmcnt(4)" ::: "memory");
    } else {
      asm volatile("s_waitcnt vmcnt(0)" ::: "memory");
    }
    __builtin_amdgcn_s_barrier();
    __builtin_amdgcn_sched_barrier(0);
    const char* ab = (const char*)(As0 + cur * 8192);
    const char* bb = (const char*)(Bs0 + cur * 8192);
#pragma unroll
    for (int ks = 0; ks < 2; ++ks) {
      long af[4], bfr[4];
      int slot16 = ks * 2 + (g >> 1);
      int soff = ((slot16 ^ (l & 3)) << 4) + half8;
#pragma unroll
      for (int mi = 0; mi < 4; ++mi) {
        int row = wr * 64 + mi * 16 + (l & 15);
        af[mi] = *(const long*)(ab + row * 64 + soff);
      }
#pragma unroll
      for (int ni = 0; ni < 4; ++ni) {
        int row = wc * 64 + ni * 16 + (l & 15);
        bfr[ni] = *(const long*)(bb + row * 64 + soff);
      }
#pragma unroll
      for (int mi = 0; mi < 4; ++mi)
#pragma unroll
        for (int ni = 0; ni < 4; ++ni)
          acc[mi][ni] = __builtin_amdgcn_mfma_f32_16x16x32_fp8_fp8(af[mi], bfr[ni], acc[mi][ni], 0, 0, 0);
    }
    __builtin_amdgcn_sched_barrier(0);
    __builtin_amdgcn_s_barrier();
    __builtin_amdgcn_sched_barrier(0);
    cur ^= 1;
  }

  // ---- softmax epilogue. row(local) = wr*64+mi*16+(l>>4)*4+j, col = wc*64+ni*16+(l&15)
  float wmax[4][4];
#pragma unroll
  for (int mi = 0; mi < 4; ++mi)
#pragma unroll
    for (int j = 0; j < 4; ++j) {
      float m = fmaxf(fmaxf(acc[mi][0][j], acc[mi][1][j]), fmaxf(acc[mi][2][j], acc[mi][3][j])) * BETA;
      m = fmaxf(m, __shfl_xor(m, 1));
      m = fmaxf(m, __shfl_xor(m, 2));
      m = fmaxf(m, __shfl_xor(m, 4));
      m = fmaxf(m, __shfl_xor(m, 8));
      wmax[mi][j] = m;
    }
  if ((l & 15) == 0) {
#pragma unroll
    for (int mi = 0; mi < 4; ++mi)
#pragma unroll
      for (int j = 0; j < 4; ++j)
        redM[wc][wr * 64 + mi * 16 + (l >> 4) * 4 + j] = wmax[mi][j];
  }
  __syncthreads();
  float fm[4][4];
#pragma unroll
  for (int mi = 0; mi < 4; ++mi)
#pragma unroll
    for (int j = 0; j < 4; ++j) {
      int row = wr * 64 + mi * 16 + (l >> 4) * 4 + j;
      fm[mi][j] = fmaxf(redM[0][row], redM[1][row]);
    }
#pragma unroll
  for (int mi = 0; mi < 4; ++mi)
#pragma unroll
    for (int j = 0; j < 4; ++j) {
      float s = 0.f;
#pragma unroll
      for (int ni = 0; ni < 4; ++ni) {
        float e = __expf(acc[mi][ni][j] * BETA - fm[mi][j]);
        acc[mi][ni][j] = e;
        s += e;
      }
      s += __shfl_xor(s, 1);
      s += __shfl_xor(s, 2);
      s += __shfl_xor(s, 4);
      s += __shfl_xor(s, 8);
      wmax[mi][j] = s;  // reuse
    }
  if ((l & 15) == 0) {
#pragma unroll
    for (int mi = 0; mi < 4; ++mi)
#pragma unroll
      for (int j = 0; j < 4; ++j)
        redS[wc][wr * 64 + mi * 16 + (l >> 4) * 4 + j] = wmax[mi][j];
  }
  __syncthreads();

  float cpart[4] = {0.f, 0.f, 0.f, 0.f};
#pragma unroll
  for (int mi = 0; mi < 4; ++mi)
#pragma unroll
    for (int j = 0; j < 4; ++j) {
      int row = wr * 64 + mi * 16 + (l >> 4) * 4 + j;
      float invs = 1.0f / (redS[0][row] + redS[1][row]);
      bool valid = (i0 + row) < NN;
#pragma unroll
      for (int ni = 0; ni < 4; ++ni) {
        unsigned char q8 = f2fp8(acc[mi][ni][j] * invs);
        if (valid) cpart[ni] += fp82f(q8);  // consistent with quantized numerator
        rT8[(wc * 64 + ni * 16 + (l & 15)) * 144 + row] = q8;
      }
    }
#pragma unroll
  for (int ni = 0; ni < 4; ++ni) {
    float c = cpart[ni];
    c += __shfl_xor(c, 16);
    c += __shfl_xor(c, 32);
    if (l < 16) crS[wr][wc * 64 + ni * 16 + l] = c;
  }
  __syncthreads();
  if (t < 128) crblk[(size_t)blockIdx.x * KK + t] = crS[0][t] + crS[1][t];

  {
    int c = t >> 1, half = t & 1;
    const unsigned char* src = &rT8[c * 144 + half * 64];
    unsigned char* dst = &rbfT8[(size_t)c * PADN + i0 + half * 64];
#pragma unroll
    for (int q = 0; q < 4; ++q)
      *(short8v*)(dst + q * 16) = *(const short8v*)(src + q * 16);
  }
  if (write_rbf) {
    int i = t >> 1, chalf = t & 1;
#pragma unroll
    for (int q = 0; q < 8; ++q) {
      unsigned int lo = 0, hi = 0;
#pragma unroll
      for (int e = 0; e < 4; ++e)
        lo |= ((unsigned int)rT8[(chalf * 64 + q * 8 + e) * 144 + i]) << (8 * e);
#pragma unroll
      for (int e = 0; e < 4; ++e)
        hi |= ((unsigned int)rT8[(chalf * 64 + q * 8 + 4 + e) * 144 + i]) << (8 * e);
      uint2 pk = {lo, hi};
      *(uint2*)&rbf8[(size_t)(i0 + i) * KK + chalf * 64 + q * 8] = pk;
    }
  }
}

// ---- FP8 MFMA mu update. chunk=128 i (128B rows), T4 vmcnt. part fp8.
__launch_bounds__(256, 2)
__global__ void muup_mfma(const unsigned char* __restrict__ rbfT8,
                          const unsigned char* __restrict__ posbT8,
                          unsigned char* __restrict__ part8) {
  __shared__ __align__(16) unsigned char smem[65536];  // As[2][16384] | Bs[2][16384]
  unsigned char* As0 = smem;
  unsigned char* Bs0 = smem + 32768;
  int t = threadIdx.x;
  int w = t >> 6, l = t & 63;
  int wr = w >> 1, wc = w & 1;
  int ht = blockIdx.x, s = blockIdx.y;

  float4v acc[4][4];
#pragma unroll
  for (int mi = 0; mi < 4; ++mi)
#pragma unroll
    for (int ni = 0; ni < 4; ++ni) acc[mi][ni] = (float4v){0.f, 0.f, 0.f, 0.f};

  int rsub = l >> 3;                          // 0..7
  int sslot = ((l & 7) ^ rsub) << 4;          // swizzled source byte slot

  auto stage = [&](int buf, int ch) {
    size_t ib = (size_t)ch * 128;
#pragma unroll
    for (int j = 0; j < 4; ++j) {
      int v = w * 4 + j;       // 0..15
      int row = v * 8 + rsub;  // 0..127
      gload16(rbfT8 + (size_t)row * PADN + ib + sslot, As0 + buf * 16384 + v * 1024);
      gload16(posbT8 + (size_t)(ht * 128 + row) * PADN + ib + sslot, Bs0 + buf * 16384 + v * 1024);
    }
  };

  int ch = s;
  stage(0, ch);  // 8 loads in flight
  int cur = 0;
  int g = l >> 4;
  int half8 = (g & 1) * 8;
  for (; ch < NCHUNK2; ch += NSPLIT) {
    int nxt = ch + NSPLIT;
    if (nxt < NCHUNK2) {
      stage(cur ^ 1, nxt);
      asm volatile("s_waitcnt vmcnt(8)" ::: "memory");
    } else {
      asm volatile("s_waitcnt vmcnt(0)" ::: "memory");
    }
    __builtin_amdgcn_s_barrier();
    __builtin_amdgcn_sched_barrier(0);
    const char* ab = (const char*)(As0 + cur * 16384);
    const char* bb = (const char*)(Bs0 + cur * 16384);
#pragma unroll
    for (int ks = 0; ks < 4; ++ks) {
      long af[4], bfr[4];
      int slot16 = ks * 2 + (g >> 1);
#pragma unroll
      for (int mi = 0; mi < 4; ++mi) {
        int row = wr * 64 + mi * 16 + (l & 15);
        af[mi] = *(const long*)(ab + row * 128 + ((slot16 ^ (l & 7)) << 4) + half8);
      }
#pragma unroll
      for (int ni = 0; ni < 4; ++ni) {
        int row = wc * 64 + ni * 16 + (l & 15);
        bfr[ni] = *(const long*)(bb + row * 128 + ((slot16 ^ (l & 7)) << 4) + half8);
      }
#pragma unroll
      for (int mi = 0; mi < 4; ++mi)
#pragma unroll
        for (int ni = 0; ni < 4; ++ni)
          acc[mi][ni] = __builtin_amdgcn_mfma_f32_16x16x32_fp8_fp8(af[mi], bfr[ni], acc[mi][ni], 0, 0, 0);
    }
    __builtin_amdgcn_sched_barrier(0);
    __builtin_amdgcn_s_barrier();
    __builtin_amdgcn_sched_barrier(0);
    cur ^= 1;
  }
#pragma unroll
  for (int mi = 0; mi < 4; ++mi)
#pragma unroll
    for (int ni = 0; ni < 4; ++ni)
#pragma unroll
      for (int j = 0; j < 4; ++j) {
        int c = wr * 64 + mi * 16 + (l >> 4) * 4 + j;
        int hh = wc * 64 + ni * 16 + (l & 15);
        part8[((size_t)s * KK + c) * HH + ht * 128 + hh] = f2fp8(acc[mi][ni][j]);
      }
}

// ---- fused fin+norm: cr = sum_b crblk; v = (sum_s part8)/cr; mub8 = fp8 normalize(v); mubT8 (last)
__global__ void finorm_kernel(const unsigned char* __restrict__ part8,
                              const float* __restrict__ crblk,
                              unsigned char* __restrict__ mub8,
                              unsigned char* __restrict__ mubT8, int write_mubT) {
  int c = blockIdx.x, t = threadIdx.x;
  __shared__ float credL[4];
  float crp = 0.f;
  for (int b = t; b < NBLK128; b += 256) crp += crblk[(size_t)b * KK + c];
  crp = wave_reduce_sum(crp);
  if ((t & 63) == 0) credL[t >> 6] = crp;
  __syncthreads();
  float cr = credL[0] + credL[1] + credL[2] + credL[3];
  float inv = 1.0f / cr;
  float s0 = 0.f, s1 = 0.f;
  const unsigned char* pb = part8 + (size_t)c * HH;
#pragma unroll 4
  for (int s2 = 0; s2 < NSPLIT; ++s2) {
    s0 += fp82f(pb[(size_t)s2 * KK * HH + t]);
    s1 += fp82f(pb[(size_t)s2 * KK * HH + t + 256]);
  }
  float v0 = s0 * inv, v1 = s1 * inv;
  if (write_mubT) {
    mubT8[(size_t)t * KK + c] = f2fp8(v0);
    mubT8[(size_t)(t + 256) * KK + c] = f2fp8(v1);
  }
  float ss = v0 * v0 + v1 * v1;
  ss = wave_reduce_sum(ss);
  __shared__ float red[4];
  if ((t & 63) == 0) red[t >> 6] = ss;
  __syncthreads();
  float rn = 1.0f / sqrtf(red[0] + red[1] + red[2] + red[3]);
  mub8[c * HH + t] = f2fp8(v0 * rn);
  mub8[c * HH + t + 256] = f2fp8(v1 * rn);
}

// ---- FP8 MFMA loss, race-proof T14 (r17 verified): BsU8 staged with vmcnt(0),
// THEN pos/neg prefetch issued; lgkmcnt-only barriers keep prefetch in flight.
__launch_bounds__(512, 4)
__global__ void loss_mfma(const unsigned char* __restrict__ rbf8,
                          const unsigned char* __restrict__ mubT8,
                          const unsigned char* __restrict__ posb8,
                          const float* __restrict__ neg,
                          const float* __restrict__ inv_norm,
                          const float* __restrict__ Wsv, float* __restrict__ loss_accum) {
  __shared__ __align__(16) unsigned char rS8[128 * 128];  // 16KB [i][c] swizzled (128B rows)
  __shared__ __align__(16) unsigned char BsU8[128 * 144]; // MFMA B [h][c] swizzled / csS [row][144]
  __shared__ float WsS[HH];
  __shared__ float pcS[128], ncS[128], pgS[128], ngS[128];
  int t = threadIdx.x;
  int w = t >> 6, l = t & 63;
  int wr = w >> 1, wc = w & 1;
  int i0 = blockIdx.x * 128;

  int rsub = l >> 3;                       // 0..7
  int sslot = ((l & 7) ^ rsub) << 4;       // swizzled source byte slot
  {
    const unsigned char* gb = rbf8 + (size_t)i0 * KK;
#pragma unroll
    for (int j = 0; j < 2; ++j) {
      int v = w * 2 + j;       // 0..15
      int row = v * 8 + rsub;  // 0..127
      gload16(gb + (size_t)row * KK + sslot, rS8 + v * 1024);
    }
  }
  WsS[t] = Wsv[t];
  if (t < 128) {
    pcS[t] = 0.f; ncS[t] = 0.f; pgS[t] = 0.f; ngS[t] = 0.f;
  }
  // full drain: rS8/WsS/init resident; nothing in flight entering the loop
  asm volatile("s_waitcnt vmcnt(0) lgkmcnt(0)" ::: "memory");
  __builtin_amdgcn_s_barrier();
  __builtin_amdgcn_sched_barrier(0);

  int g = l >> 4;
  int half8 = (g & 1) * 8;
  int rl = t >> 2, q = t & 3;
  int gi = i0 + rl;
  bool vld = gi < NN;
  int gcl = vld ? gi : (NN - 1);  // clamped row: unconditional prefetch loads
  const unsigned char* prb = posb8 + (size_t)gcl * HH;
  const float* nrb = neg + (size_t)gcl * HH;

  for (int p = 0; p < 4; ++p) {
    // stage BsU8 (the only vmem in flight right now)
    {
      const unsigned char* gb = mubT8 + (size_t)p * 128 * KK;
#pragma unroll
      for (int j = 0; j < 2; ++j) {
        int v = w * 2 + j;
        int row = v * 8 + rsub;
        gload16(gb + (size_t)row * KK + sslot, BsU8 + v * 1024);
      }
    }
    asm volatile("s_waitcnt vmcnt(0)" ::: "memory");  // drains only the 2 gload16
    __builtin_amdgcn_s_barrier();                     // BsU8 ready for all waves
    __builtin_amdgcn_sched_barrier(0);

    // prefetch this pass's pos/neg into registers; consumed in dot phase
    uint2 pv8[4];
    float4 nv0[4], nv1[4];
#pragma unroll
    for (int e = 0; e < 4; ++e) {
      int cb = e * 32 + q * 8;
      pv8[e] = *(const uint2*)(prb + p * 128 + cb);
      nv0[e] = *(const float4*)(nrb + p * 128 + cb);
      nv1[e] = *(const float4*)(nrb + p * 128 + cb + 4);
    }
    __builtin_amdgcn_sched_barrier(0);  // pin issue point before MFMA phase

    float4v acc[2][4];
#pragma unroll
    for (int mi = 0; mi < 2; ++mi)
#pragma unroll
      for (int ni = 0; ni < 4; ++ni) acc[mi][ni] = (float4v){0.f, 0.f, 0.f, 0.f};

#pragma unroll
    for (int ks = 0; ks < 4; ++ks) {
      long af[2], bfr[4];
      int slot16 = ks * 2 + (g >> 1);
      int soff = ((slot16 ^ (l & 7)) << 4) + half8;
#pragma unroll
      for (int mi = 0; mi < 2; ++mi) {
        int row = wr * 32 + mi * 16 + (l & 15);  // i row in rS8
        af[mi] = *(const long*)((const char*)rS8 + row * 128 + soff);
      }
#pragma unroll
      for (int ni = 0; ni < 4; ++ni) {
        int hrow = wc * 64 + ni * 16 + (l & 15);  // h row in BsU8
        bfr[ni] = *(const long*)((const char*)BsU8 + hrow * 128 + soff);
      }
#pragma unroll
      for (int mi = 0; mi < 2; ++mi)
#pragma unroll
        for (int ni = 0; ni < 4; ++ni)
          acc[mi][ni] = __builtin_amdgcn_mfma_f32_16x16x32_fp8_fp8(af[mi], bfr[ni], acc[mi][ni], 0, 0, 0);
    }
    // (c) MFMA LDS reads done before sigma overwrites BsU8 (lgkm only; prefetch stays in flight)
    asm volatile("s_waitcnt lgkmcnt(0)" ::: "memory");
    __builtin_amdgcn_s_barrier();
    __builtin_amdgcn_sched_barrier(0);

    unsigned char* csS = BsU8;
#pragma unroll
    for (int mi = 0; mi < 2; ++mi)
#pragma unroll
      for (int ni = 0; ni < 4; ++ni)
#pragma unroll
        for (int j = 0; j < 4; ++j) {
          int row = wr * 32 + mi * 16 + (l >> 4) * 4 + j;
          int col = wc * 64 + ni * 16 + (l & 15);
          csS[row * 144 + col] = f2fp8(1.0f / (1.0f + __expf(-acc[mi][ni][j])));
        }
    // (d) sigma writes visible before dot-phase reads (lgkm only)
    asm volatile("s_waitcnt lgkmcnt(0)" ::: "memory");
    __builtin_amdgcn_s_barrier();
    __builtin_amdgcn_sched_barrier(0);

    {
      float pc = 0.f, nc = 0.f, pg = 0.f, ng = 0.f;
      const unsigned char* cr = csS + rl * 144;
#pragma unroll
      for (int e = 0; e < 4; ++e) {
        int cb = e * 32 + q * 8;
        uint2 cs8 = *(const uint2*)(cr + cb);
        float sf[8], pf[8];
        CVT8_FP8(sf, cs8)
        CVT8_FP8(pf, pv8[e])
#pragma unroll
        for (int u = 0; u < 8; ++u) {
          float nv = (u < 4) ? (&nv0[e].x)[u] : (&nv1[e].x)[u - 4];
          float wv = WsS[p * 128 + cb + u];
          pc = fmaf(sf[u], pf[u], pc);
          nc = fmaf(sf[u], nv, nc);
          pg = fmaf(wv, pf[u], pg);
          ng = fmaf(wv, nv, ng);
        }
      }
      if (!vld) { pc = 0.f; nc = 0.f; pg = 0.f; ng = 0.f; }
      pc += __shfl_xor(pc, 1); pc += __shfl_xor(pc, 2);
      nc += __shfl_xor(nc, 1); nc += __shfl_xor(nc, 2);
      pg += __shfl_xor(pg, 1); pg += __shfl_xor(pg, 2);
      ng += __shfl_xor(ng, 1); ng += __shfl_xor(ng, 2);
      if (q == 0) {
        pcS[rl] += pc;
        ncS[rl] += nc;
        pgS[rl] += pg;
        ngS[rl] += ng;
      }
    }
    // bottom: dot-phase LDS reads done before next pass's gload16 overwrites BsU8
    asm volatile("s_waitcnt lgkmcnt(0)" ::: "memory");
    __builtin_amdgcn_s_barrier();
    __builtin_amdgcn_sched_barrier(0);
  }
  __syncthreads();
  if (t < 128) {
    int gi2 = i0 + t;
    float contrib = 0.f;
    if (gi2 < NN) {
      float nrm = 1.0f / inv_norm[gi2];  // ||pos||+eps: un-normalization
      float pg = pgS[t] * nrm;
      float pc = pcS[t] * nrm;
      float ng = ngS[t];
      float nc = ncS[t];
      contrib = 0.5f * (softplusf(-pg) + softplusf(ng)) +
                0.5f * (softplusf(-pc) + softplusf(nc));
    }
    contrib = wave_reduce_sum(contrib);
    if (l == 0) atomicAdd(loss_accum, contrib);
  }
}

__global__ void out_kernel(const float* __restrict__ loss_accum, float* __restrict__ out) {
  out[0] = loss_accum[0] * (1.0f / NN);
}

extern "C" void kernel_launch(void* const* d_in, const int* in_sizes, int n_in,
                              void* d_out, int out_size, void* d_ws, size_t ws_size,
                              hipStream_t stream) {
  const float* pos = (const float*)d_in[0];
  const float* neg = (const float*)d_in[1];
  const float* init = (const float*)d_in[2];
  const float* W = (const float*)d_in[3];
  float* out = (float*)d_out;

  char* ws = (char*)d_ws;
  size_t off = 0;
  auto alloc = [&](size_t bytes) {
    void* p = ws + off;
    off = (off + bytes + 255) & ~(size_t)255;
    return p;
  };
  unsigned char* posb8 = (unsigned char*)alloc((size_t)PADN * HH);        // 51.2 MB
  unsigned short* posbb = (unsigned short*)alloc((size_t)PADN * HH * 2);  // 102.5 MB
  unsigned char* posbT8 = (unsigned char*)alloc((size_t)HH * PADN);       // 51.2 MB
  unsigned char* rbf8 = (unsigned char*)alloc((size_t)PADN * KK);         // 12.8 MB
  unsigned char* rbfT8 = (unsigned char*)alloc((size_t)KK * PADN);        // 12.8 MB
  unsigned char* part8 = (unsigned char*)alloc((size_t)NSPLIT * KK * HH); // 8.4 MB
  float* colpart = (float*)alloc((size_t)PREPB * HH * 4);                 // 2 MB
  float* crblk = (float*)alloc((size_t)NBLK128 * KK * 4);                 // 400 KB
  float* inv_norm = (float*)alloc((size_t)NN * 4);
  unsigned char* mub8 = (unsigned char*)alloc((size_t)KK * HH);
  unsigned char* mubT8 = (unsigned char*)alloc((size_t)KK * HH);
  float* gs = (float*)alloc(HH * 4);
  float* Ws = (float*)alloc(HH * 4);
  float* loss_accum = (float*)alloc(16);

  hipMemsetAsync(loss_accum, 0, sizeof(float), stream);

  prep_kernel<<<PREPB, 256, 0, stream>>>(pos, inv_norm, colpart, posbb, posb8);
  transpose_kernel<<<dim3(PADN / 64, HH / 64), 256, 0, stream>>>(posbb, posbT8);
  gs_kernel<<<1, 512, 0, stream>>>(colpart, gs);
  wsum_kernel<<<128, 256, 0, stream>>>(W, gs, Ws);

  norm_mu_kernel<<<KK, 256, 0, stream>>>(init, mub8);
  for (int it = 0; it < ITERS; ++it) {
    dist_mfma<<<NBLK128, 256, 0, stream>>>(posb8, mub8, rbf8, rbfT8, crblk, it == ITERS - 1 ? 1 : 0);
    muup_mfma<<<dim3(4, NSPLIT), 256, 0, stream>>>(rbfT8, posbT8, part8);
    finorm_kernel<<<KK, 256, 0, stream>>>(part8, crblk, mub8, mubT8, it == ITERS - 1 ? 1 : 0);
  }

  loss_mfma<<<NBLK128, 512, 0, stream>>>(rbf8, mubT8, posb8, neg, inv_norm, Ws, loss_accum);
  out_kernel<<<1, 1, 0, stream>>>(loss_accum, out);
}

// Round 20
// 926.295 us; speedup vs baseline: 1.0692x; 1.0200x over previous
//
#include <hip/hip_runtime.h>
#include <math.h>

#define NN 100000
#define PADN 100096    // 782*128
#define NBLK128 782
#define HH 512
#define KK 128
#define BETA 100.0f
#define EPSF 1e-8f
#define ITERS 11
#define NSPLIT 128
#define NCHUNK2 (PADN / 128)  // 782
#define PREPB 1024

typedef __attribute__((ext_vector_type(8))) short short8v;
typedef __attribute__((ext_vector_type(4))) float float4v;

typedef const __attribute__((address_space(1))) void* gas_t;
typedef __attribute__((address_space(3))) void* las_t;

__device__ __forceinline__ void gload16(const void* g, void* l) {
  __builtin_amdgcn_global_load_lds((gas_t)g, (las_t)l, 16, 0, 0);
}

__device__ __forceinline__ unsigned short f2bf(float x) {
  unsigned int u = __float_as_uint(x);
  unsigned int r = (u + 0x7fff + ((u >> 16) & 1)) >> 16;
  return (unsigned short)r;
}
__device__ __forceinline__ float bf2f(unsigned short b) {
  return __uint_as_float((unsigned int)b << 16);
}
__device__ __forceinline__ unsigned char f2fp8(float x) {
  return (unsigned char)(__builtin_amdgcn_cvt_pk_fp8_f32(x, x, 0, false) & 0xff);
}
__device__ __forceinline__ float fp82f(unsigned char b) {
  return __builtin_amdgcn_cvt_f32_fp8((unsigned int)b, 0);
}
// convert 8 packed fp8 (uint2) -> float[8] with literal selectors
#define CVT8_FP8(dst, pv)                                      \
  dst[0] = __builtin_amdgcn_cvt_f32_fp8((pv).x, 0);            \
  dst[1] = __builtin_amdgcn_cvt_f32_fp8((pv).x, 1);            \
  dst[2] = __builtin_amdgcn_cvt_f32_fp8((pv).x, 2);            \
  dst[3] = __builtin_amdgcn_cvt_f32_fp8((pv).x, 3);            \
  dst[4] = __builtin_amdgcn_cvt_f32_fp8((pv).y, 0);            \
  dst[5] = __builtin_amdgcn_cvt_f32_fp8((pv).y, 1);            \
  dst[6] = __builtin_amdgcn_cvt_f32_fp8((pv).y, 2);            \
  dst[7] = __builtin_amdgcn_cvt_f32_fp8((pv).y, 3);

__device__ __forceinline__ float wave_reduce_sum(float v) {
#pragma unroll
  for (int off = 32; off > 0; off >>= 1) v += __shfl_xor(v, off);
  return v;
}
__device__ __forceinline__ float softplusf(float x) {
  return fmaxf(x, 0.0f) + log1pf(expf(-fabsf(x)));
}

// ---- fused prep: inv_norm, colpart, posb8 (fp8 normalized), pad-zero
__global__ void prep_kernel(const float* __restrict__ pos,
                            float* __restrict__ inv_norm,
                            float* __restrict__ colpart,
                            unsigned char* __restrict__ posb8) {
  int t = threadIdx.x;
  int w = t >> 6, lane = t & 63;
  int gw = blockIdx.x * 4 + w;
  float cpart[8] = {0, 0, 0, 0, 0, 0, 0, 0};
  for (int row = gw; row < NN; row += PREPB * 4) {
    const float* p = pos + (size_t)row * HH + lane * 8;
    float4 f0 = *(const float4*)p;
    float4 f1 = *(const float4*)(p + 4);
    float v[8] = {f0.x, f0.y, f0.z, f0.w, f1.x, f1.y, f1.z, f1.w};
    float ss = 0.f;
#pragma unroll
    for (int u = 0; u < 8; ++u) {
      ss += v[u] * v[u];
      cpart[u] += v[u];
    }
    ss = wave_reduce_sum(ss);
    float inv = 1.0f / (sqrtf(ss) + EPSF);
    if (lane == 0) inv_norm[row] = inv;
    int p0 = 0, p1 = 0;
    p0 = __builtin_amdgcn_cvt_pk_fp8_f32(v[0] * inv, v[1] * inv, p0, false);
    p0 = __builtin_amdgcn_cvt_pk_fp8_f32(v[2] * inv, v[3] * inv, p0, true);
    p1 = __builtin_amdgcn_cvt_pk_fp8_f32(v[4] * inv, v[5] * inv, p1, false);
    p1 = __builtin_amdgcn_cvt_pk_fp8_f32(v[6] * inv, v[7] * inv, p1, true);
    int2 pk = {p0, p1};
    *(int2*)&posb8[(size_t)row * HH + lane * 8] = pk;
  }
  {
    int idx = blockIdx.x * 256 + t;
    if (idx < (PADN - NN) * HH / 16) {
      int4 z4 = {0, 0, 0, 0};
      *(int4*)&posb8[(size_t)NN * HH + idx * 16] = z4;
    }
  }
  __shared__ float cs[HH];
  cs[t] = 0.f;
  cs[t + 256] = 0.f;
  __syncthreads();
#pragma unroll
  for (int u = 0; u < 8; ++u) atomicAdd(&cs[lane * 8 + u], cpart[u]);
  __syncthreads();
  colpart[(size_t)blockIdx.x * HH + t] = cs[t];
  colpart[(size_t)blockIdx.x * HH + t + 256] = cs[t + 256];
}

// ---- byte transpose posb8 -> posbT8 (single rounding; posb8 is L2/L3-hot)
__launch_bounds__(256)
__global__ void transpose_kernel(const unsigned char* __restrict__ posb8,
                                 unsigned char* __restrict__ posbT8) {
  __shared__ unsigned char tile8[64][80];  // pad 16: rows 16B-aligned
  int t = threadIdx.x;
  int i0 = blockIdx.x * 64, h0 = blockIdx.y * 64;
  int r = t >> 2, cq = (t & 3) * 16;
  {
    uint4 v = *(const uint4*)&posb8[(size_t)(i0 + r) * HH + h0 + cq];
    const unsigned char* vb = (const unsigned char*)&v;
#pragma unroll
    for (int e = 0; e < 16; ++e) tile8[cq + e][r] = vb[e];
  }
  __syncthreads();
  int h = t >> 2, iq = (t & 3) * 16;
  *(uint4*)&posbT8[(size_t)(h0 + h) * PADN + i0 + iq] = *(const uint4*)&tile8[h][iq];
}

// ---- gs[h] = sigmoid(sum_b colpart[b][h] / N)
__global__ void gs_kernel(const float* __restrict__ colpart, float* __restrict__ gs) {
  int t = threadIdx.x;  // 512
  float s = 0.f;
  for (int b = 0; b < PREPB; ++b) s += colpart[(size_t)b * HH + t];
  float m = s * (1.0f / NN);
  gs[t] = 1.0f / (1.0f + expf(-m));
}

// ---- Ws[j] = sum_h W[j][h]*gs[h]
__global__ void wsum_kernel(const float* __restrict__ W, const float* __restrict__ gs,
                            float* __restrict__ Ws) {
  int w = threadIdx.x >> 6, lane = threadIdx.x & 63;
  int row = blockIdx.x * 4 + w;
  const float* Wr = W + (size_t)row * HH;
  float s = 0.f;
#pragma unroll
  for (int j = 0; j < 8; ++j) s += Wr[lane + 64 * j] * gs[lane + 64 * j];
  s = wave_reduce_sum(s);
  if (lane == 0) Ws[row] = s;
}

// ---- mub8 (fp8) = row / ||row|| from fp32 src. Used once on init.
__global__ void norm_mu_kernel(const float* __restrict__ src, unsigned char* __restrict__ mub8) {
  int k = blockIdx.x, t = threadIdx.x;
  float v0 = src[k * HH + t], v1 = src[k * HH + t + 256];
  float ss = v0 * v0 + v1 * v1;
  ss = wave_reduce_sum(ss);
  __shared__ float red[4];
  if ((t & 63) == 0) red[t >> 6] = ss;
  __syncthreads();
  float inv = 1.0f / sqrtf(red[0] + red[1] + red[2] + red[3]);
  mub8[k * HH + t] = f2fp8(v0 * inv);
  mub8[k * HH + t + 256] = f2fp8(v1 * inv);
}

// ---- FP8 MFMA dist + fused softmax. BM=128, chunk=64 k (64B rows), 8 chunks, T4 vmcnt.
__launch_bounds__(256, 4)
__global__ void dist_mfma(const unsigned char* __restrict__ posb8,
                          const unsigned char* __restrict__ mub8,
                          unsigned char* __restrict__ rbf8,
                          unsigned char* __restrict__ rbfT8,
                          float* __restrict__ crblk,
                          int write_rbf) {
  __shared__ __align__(16) unsigned char smem[32768];  // As[2][8192] | Bs[2][8192]
  unsigned char* As0 = smem;
  unsigned char* Bs0 = smem + 16384;
  unsigned char* rT8 = smem;  // [128 c][144] epilogue alias (18.4KB)
  __shared__ float redM[2][128];
  __shared__ float redS[2][128];
  __shared__ float crS[2][128];

  int t = threadIdx.x;
  int w = t >> 6, l = t & 63;
  int wr = w >> 1, wc = w & 1;
  int i0 = blockIdx.x * 128;

  float4v acc[4][4];
#pragma unroll
  for (int mi = 0; mi < 4; ++mi)
#pragma unroll
    for (int ni = 0; ni < 4; ++ni) acc[mi][ni] = (float4v){0.f, 0.f, 0.f, 0.f};

  int rsub = l >> 2;                          // staged row within 16-row v-group
  int sslot = ((l & 3) ^ (rsub & 3)) << 4;    // swizzled source byte slot

  auto stage = [&](int buf, int ch) {
    int h0 = ch * 64;
#pragma unroll
    for (int j = 0; j < 2; ++j) {
      int v = w * 2 + j;        // 0..7
      int row = v * 16 + rsub;  // 0..127
      gload16(posb8 + (size_t)(i0 + row) * HH + h0 + sslot, As0 + buf * 8192 + v * 1024);
      gload16(mub8 + (size_t)row * HH + h0 + sslot, Bs0 + buf * 8192 + v * 1024);
    }
  };

  stage(0, 0);  // 4 loads in flight
  int cur = 0;
  int g = l >> 4;
  int half8 = (g & 1) * 8;
  for (int ch = 0; ch < 8; ++ch) {
    if (ch < 7) {
      stage(cur ^ 1, ch + 1);  // 8 outstanding
      asm volatile("s_waitcnt vmcnt(4)" ::: "memory");
    } else {
      asm volatile("s_waitcnt vmcnt(0)" ::: "memory");
    }
    __builtin_amdgcn_s_barrier();
    __builtin_amdgcn_sched_barrier(0);
    const char* ab = (const char*)(As0 + cur * 8192);
    const char* bb = (const char*)(Bs0 + cur * 8192);
#pragma unroll
    for (int ks = 0; ks < 2; ++ks) {
      long af[4], bfr[4];
      int slot16 = ks * 2 + (g >> 1);
      int soff = ((slot16 ^ (l & 3)) << 4) + half8;
#pragma unroll
      for (int mi = 0; mi < 4; ++mi) {
        int row = wr * 64 + mi * 16 + (l & 15);
        af[mi] = *(const long*)(ab + row * 64 + soff);
      }
#pragma unroll
      for (int ni = 0; ni < 4; ++ni) {
        int row = wc * 64 + ni * 16 + (l & 15);
        bfr[ni] = *(const long*)(bb + row * 64 + soff);
      }
#pragma unroll
      for (int mi = 0; mi < 4; ++mi)
#pragma unroll
        for (int ni = 0; ni < 4; ++ni)
          acc[mi][ni] = __builtin_amdgcn_mfma_f32_16x16x32_fp8_fp8(af[mi], bfr[ni], acc[mi][ni], 0, 0, 0);
    }
    __builtin_amdgcn_sched_barrier(0);
    __builtin_amdgcn_s_barrier();
    __builtin_amdgcn_sched_barrier(0);
    cur ^= 1;
  }

  // ---- softmax epilogue. row(local) = wr*64+mi*16+(l>>4)*4+j, col = wc*64+ni*16+(l&15)
  float wmax[4][4];
#pragma unroll
  for (int mi = 0; mi < 4; ++mi)
#pragma unroll
    for (int j = 0; j < 4; ++j) {
      float m = fmaxf(fmaxf(acc[mi][0][j], acc[mi][1][j]), fmaxf(acc[mi][2][j], acc[mi][3][j])) * BETA;
      m = fmaxf(m, __shfl_xor(m, 1));
      m = fmaxf(m, __shfl_xor(m, 2));
      m = fmaxf(m, __shfl_xor(m, 4));
      m = fmaxf(m, __shfl_xor(m, 8));
      wmax[mi][j] = m;
    }
  if ((l & 15) == 0) {
#pragma unroll
    for (int mi = 0; mi < 4; ++mi)
#pragma unroll
      for (int j = 0; j < 4; ++j)
        redM[wc][wr * 64 + mi * 16 + (l >> 4) * 4 + j] = wmax[mi][j];
  }
  __syncthreads();
  float fm[4][4];
#pragma unroll
  for (int mi = 0; mi < 4; ++mi)
#pragma unroll
    for (int j = 0; j < 4; ++j) {
      int row = wr * 64 + mi * 16 + (l >> 4) * 4 + j;
      fm[mi][j] = fmaxf(redM[0][row], redM[1][row]);
    }
#pragma unroll
  for (int mi = 0; mi < 4; ++mi)
#pragma unroll
    for (int j = 0; j < 4; ++j) {
      float s = 0.f;
#pragma unroll
      for (int ni = 0; ni < 4; ++ni) {
        float e = __expf(acc[mi][ni][j] * BETA - fm[mi][j]);
        acc[mi][ni][j] = e;
        s += e;
      }
      s += __shfl_xor(s, 1);
      s += __shfl_xor(s, 2);
      s += __shfl_xor(s, 4);
      s += __shfl_xor(s, 8);
      wmax[mi][j] = s;  // reuse
    }
  if ((l & 15) == 0) {
#pragma unroll
    for (int mi = 0; mi < 4; ++mi)
#pragma unroll
      for (int j = 0; j < 4; ++j)
        redS[wc][wr * 64 + mi * 16 + (l >> 4) * 4 + j] = wmax[mi][j];
  }
  __syncthreads();

  float cpart[4] = {0.f, 0.f, 0.f, 0.f};
#pragma unroll
  for (int mi = 0; mi < 4; ++mi)
#pragma unroll
    for (int j = 0; j < 4; ++j) {
      int row = wr * 64 + mi * 16 + (l >> 4) * 4 + j;
      float invs = 1.0f / (redS[0][row] + redS[1][row]);
      bool valid = (i0 + row) < NN;
#pragma unroll
      for (int ni = 0; ni < 4; ++ni) {
        unsigned char q8 = f2fp8(acc[mi][ni][j] * invs);
        if (valid) cpart[ni] += fp82f(q8);  // consistent with quantized numerator
        rT8[(wc * 64 + ni * 16 + (l & 15)) * 144 + row] = q8;
      }
    }
#pragma unroll
  for (int ni = 0; ni < 4; ++ni) {
    float c = cpart[ni];
    c += __shfl_xor(c, 16);
    c += __shfl_xor(c, 32);
    if (l < 16) crS[wr][wc * 64 + ni * 16 + l] = c;
  }
  __syncthreads();
  if (t < 128) crblk[(size_t)blockIdx.x * KK + t] = crS[0][t] + crS[1][t];

  {
    int c = t >> 1, half = t & 1;
    const unsigned char* src = &rT8[c * 144 + half * 64];
    unsigned char* dst = &rbfT8[(size_t)c * PADN + i0 + half * 64];
#pragma unroll
    for (int q = 0; q < 4; ++q)
      *(short8v*)(dst + q * 16) = *(const short8v*)(src + q * 16);
  }
  if (write_rbf) {
    int i = t >> 1, chalf = t & 1;
#pragma unroll
    for (int q = 0; q < 8; ++q) {
      unsigned int lo = 0, hi = 0;
#pragma unroll
      for (int e = 0; e < 4; ++e)
        lo |= ((unsigned int)rT8[(chalf * 64 + q * 8 + e) * 144 + i]) << (8 * e);
#pragma unroll
      for (int e = 0; e < 4; ++e)
        hi |= ((unsigned int)rT8[(chalf * 64 + q * 8 + 4 + e) * 144 + i]) << (8 * e);
      uint2 pk = {lo, hi};
      *(uint2*)&rbf8[(size_t)(i0 + i) * KK + chalf * 64 + q * 8] = pk;
    }
  }
}

// ---- FP8 MFMA mu update. chunk=128 i (128B rows), T4 vmcnt. part fp8.
__launch_bounds__(256, 2)
__global__ void muup_mfma(const unsigned char* __restrict__ rbfT8,
                          const unsigned char* __restrict__ posbT8,
                          unsigned char* __restrict__ part8) {
  __shared__ __align__(16) unsigned char smem[65536];  // As[2][16384] | Bs[2][16384]
  unsigned char* As0 = smem;
  unsigned char* Bs0 = smem + 32768;
  int t = threadIdx.x;
  int w = t >> 6, l = t & 63;
  int wr = w >> 1, wc = w & 1;
  int ht = blockIdx.x, s = blockIdx.y;

  float4v acc[4][4];
#pragma unroll
  for (int mi = 0; mi < 4; ++mi)
#pragma unroll
    for (int ni = 0; ni < 4; ++ni) acc[mi][ni] = (float4v){0.f, 0.f, 0.f, 0.f};

  int rsub = l >> 3;                          // 0..7
  int sslot = ((l & 7) ^ rsub) << 4;          // swizzled source byte slot

  auto stage = [&](int buf, int ch) {
    size_t ib = (size_t)ch * 128;
#pragma unroll
    for (int j = 0; j < 4; ++j) {
      int v = w * 4 + j;       // 0..15
      int row = v * 8 + rsub;  // 0..127
      gload16(rbfT8 + (size_t)row * PADN + ib + sslot, As0 + buf * 16384 + v * 1024);
      gload16(posbT8 + (size_t)(ht * 128 + row) * PADN + ib + sslot, Bs0 + buf * 16384 + v * 1024);
    }
  };

  int ch = s;
  stage(0, ch);  // 8 loads in flight
  int cur = 0;
  int g = l >> 4;
  int half8 = (g & 1) * 8;
  for (; ch < NCHUNK2; ch += NSPLIT) {
    int nxt = ch + NSPLIT;
    if (nxt < NCHUNK2) {
      stage(cur ^ 1, nxt);
      asm volatile("s_waitcnt vmcnt(8)" ::: "memory");
    } else {
      asm volatile("s_waitcnt vmcnt(0)" ::: "memory");
    }
    __builtin_amdgcn_s_barrier();
    __builtin_amdgcn_sched_barrier(0);
    const char* ab = (const char*)(As0 + cur * 16384);
    const char* bb = (const char*)(Bs0 + cur * 16384);
#pragma unroll
    for (int ks = 0; ks < 4; ++ks) {
      long af[4], bfr[4];
      int slot16 = ks * 2 + (g >> 1);
#pragma unroll
      for (int mi = 0; mi < 4; ++mi) {
        int row = wr * 64 + mi * 16 + (l & 15);
        af[mi] = *(const long*)(ab + row * 128 + ((slot16 ^ (l & 7)) << 4) + half8);
      }
#pragma unroll
      for (int ni = 0; ni < 4; ++ni) {
        int row = wc * 64 + ni * 16 + (l & 15);
        bfr[ni] = *(const long*)(bb + row * 128 + ((slot16 ^ (l & 7)) << 4) + half8);
      }
#pragma unroll
      for (int mi = 0; mi < 4; ++mi)
#pragma unroll
        for (int ni = 0; ni < 4; ++ni)
          acc[mi][ni] = __builtin_amdgcn_mfma_f32_16x16x32_fp8_fp8(af[mi], bfr[ni], acc[mi][ni], 0, 0, 0);
    }
    __builtin_amdgcn_sched_barrier(0);
    __builtin_amdgcn_s_barrier();
    __builtin_amdgcn_sched_barrier(0);
    cur ^= 1;
  }
#pragma unroll
  for (int mi = 0; mi < 4; ++mi)
#pragma unroll
    for (int ni = 0; ni < 4; ++ni)
#pragma unroll
      for (int j = 0; j < 4; ++j) {
        int c = wr * 64 + mi * 16 + (l >> 4) * 4 + j;
        int hh = wc * 64 + ni * 16 + (l & 15);
        part8[((size_t)s * KK + c) * HH + ht * 128 + hh] = f2fp8(acc[mi][ni][j]);
      }
}

// ---- fused fin+norm: cr = sum_b crblk; v = (sum_s part8)/cr; mub8 = fp8 normalize(v); mubT8 (last)
__global__ void finorm_kernel(const unsigned char* __restrict__ part8,
                              const float* __restrict__ crblk,
                              unsigned char* __restrict__ mub8,
                              unsigned char* __restrict__ mubT8, int write_mubT) {
  int c = blockIdx.x, t = threadIdx.x;
  __shared__ float credL[4];
  float crp = 0.f;
  for (int b = t; b < NBLK128; b += 256) crp += crblk[(size_t)b * KK + c];
  crp = wave_reduce_sum(crp);
  if ((t & 63) == 0) credL[t >> 6] = crp;
  __syncthreads();
  float cr = credL[0] + credL[1] + credL[2] + credL[3];
  float inv = 1.0f / cr;
  float s0 = 0.f, s1 = 0.f;
  const unsigned char* pb = part8 + (size_t)c * HH;
#pragma unroll 4
  for (int s2 = 0; s2 < NSPLIT; ++s2) {
    s0 += fp82f(pb[(size_t)s2 * KK * HH + t]);
    s1 += fp82f(pb[(size_t)s2 * KK * HH + t + 256]);
  }
  float v0 = s0 * inv, v1 = s1 * inv;
  if (write_mubT) {
    mubT8[(size_t)t * KK + c] = f2fp8(v0);
    mubT8[(size_t)(t + 256) * KK + c] = f2fp8(v1);
  }
  float ss = v0 * v0 + v1 * v1;
  ss = wave_reduce_sum(ss);
  __shared__ float red[4];
  if ((t & 63) == 0) red[t >> 6] = ss;
  __syncthreads();
  float rn = 1.0f / sqrtf(red[0] + red[1] + red[2] + red[3]);
  mub8[c * HH + t] = f2fp8(v0 * rn);
  mub8[c * HH + t + 256] = f2fp8(v1 * rn);
}

// ---- FP8 MFMA loss, race-proof T14 (r17 verified): BsU8 staged with vmcnt(0),
// THEN pos/neg prefetch issued; lgkmcnt-only barriers keep prefetch in flight.
__launch_bounds__(512, 4)
__global__ void loss_mfma(const unsigned char* __restrict__ rbf8,
                          const unsigned char* __restrict__ mubT8,
                          const unsigned char* __restrict__ posb8,
                          const float* __restrict__ neg,
                          const float* __restrict__ inv_norm,
                          const float* __restrict__ Wsv, float* __restrict__ loss_accum) {
  __shared__ __align__(16) unsigned char rS8[128 * 128];  // 16KB [i][c] swizzled (128B rows)
  __shared__ __align__(16) unsigned char BsU8[128 * 144]; // MFMA B [h][c] swizzled / csS [row][144]
  __shared__ float WsS[HH];
  __shared__ float pcS[128], ncS[128], pgS[128], ngS[128];
  int t = threadIdx.x;
  int w = t >> 6, l = t & 63;
  int wr = w >> 1, wc = w & 1;
  int i0 = blockIdx.x * 128;

  int rsub = l >> 3;                       // 0..7
  int sslot = ((l & 7) ^ rsub) << 4;       // swizzled source byte slot
  {
    const unsigned char* gb = rbf8 + (size_t)i0 * KK;
#pragma unroll
    for (int j = 0; j < 2; ++j) {
      int v = w * 2 + j;       // 0..15
      int row = v * 8 + rsub;  // 0..127
      gload16(gb + (size_t)row * KK + sslot, rS8 + v * 1024);
    }
  }
  WsS[t] = Wsv[t];
  if (t < 128) {
    pcS[t] = 0.f; ncS[t] = 0.f; pgS[t] = 0.f; ngS[t] = 0.f;
  }
  // full drain: rS8/WsS/init resident; nothing in flight entering the loop
  asm volatile("s_waitcnt vmcnt(0) lgkmcnt(0)" ::: "memory");
  __builtin_amdgcn_s_barrier();
  __builtin_amdgcn_sched_barrier(0);

  int g = l >> 4;
  int half8 = (g & 1) * 8;
  int rl = t >> 2, q = t & 3;
  int gi = i0 + rl;
  bool vld = gi < NN;
  int gcl = vld ? gi : (NN - 1);  // clamped row: unconditional prefetch loads
  const unsigned char* prb = posb8 + (size_t)gcl * HH;
  const float* nrb = neg + (size_t)gcl * HH;

  for (int p = 0; p < 4; ++p) {
    // stage BsU8 (the only vmem in flight right now)
    {
      const unsigned char* gb = mubT8 + (size_t)p * 128 * KK;
#pragma unroll
      for (int j = 0; j < 2; ++j) {
        int v = w * 2 + j;
        int row = v * 8 + rsub;
        gload16(gb + (size_t)row * KK + sslot, BsU8 + v * 1024);
      }
    }
    asm volatile("s_waitcnt vmcnt(0)" ::: "memory");  // drains only the 2 gload16
    __builtin_amdgcn_s_barrier();                     // BsU8 ready for all waves
    __builtin_amdgcn_sched_barrier(0);

    // prefetch this pass's pos/neg into registers; consumed in dot phase
    uint2 pv8[4];
    float4 nv0[4], nv1[4];
#pragma unroll
    for (int e = 0; e < 4; ++e) {
      int cb = e * 32 + q * 8;
      pv8[e] = *(const uint2*)(prb + p * 128 + cb);
      nv0[e] = *(const float4*)(nrb + p * 128 + cb);
      nv1[e] = *(const float4*)(nrb + p * 128 + cb + 4);
    }
    __builtin_amdgcn_sched_barrier(0);  // pin issue point before MFMA phase

    float4v acc[2][4];
#pragma unroll
    for (int mi = 0; mi < 2; ++mi)
#pragma unroll
      for (int ni = 0; ni < 4; ++ni) acc[mi][ni] = (float4v){0.f, 0.f, 0.f, 0.f};

#pragma unroll
    for (int ks = 0; ks < 4; ++ks) {
      long af[2], bfr[4];
      int slot16 = ks * 2 + (g >> 1);
      int soff = ((slot16 ^ (l & 7)) << 4) + half8;
#pragma unroll
      for (int mi = 0; mi < 2; ++mi) {
        int row = wr * 32 + mi * 16 + (l & 15);  // i row in rS8
        af[mi] = *(const long*)((const char*)rS8 + row * 128 + soff);
      }
#pragma unroll
      for (int ni = 0; ni < 4; ++ni) {
        int hrow = wc * 64 + ni * 16 + (l & 15);  // h row in BsU8
        bfr[ni] = *(const long*)((const char*)BsU8 + hrow * 128 + soff);
      }
#pragma unroll
      for (int mi = 0; mi < 2; ++mi)
#pragma unroll
        for (int ni = 0; ni < 4; ++ni)
          acc[mi][ni] = __builtin_amdgcn_mfma_f32_16x16x32_fp8_fp8(af[mi], bfr[ni], acc[mi][ni], 0, 0, 0);
    }
    // (c) MFMA LDS reads done before sigma overwrites BsU8 (lgkm only; prefetch stays in flight)
    asm volatile("s_waitcnt lgkmcnt(0)" ::: "memory");
    __builtin_amdgcn_s_barrier();
    __builtin_amdgcn_sched_barrier(0);

    unsigned char* csS = BsU8;
#pragma unroll
    for (int mi = 0; mi < 2; ++mi)
#pragma unroll
      for (int ni = 0; ni < 4; ++ni)
#pragma unroll
        for (int j = 0; j < 4; ++j) {
          int row = wr * 32 + mi * 16 + (l >> 4) * 4 + j;
          int col = wc * 64 + ni * 16 + (l & 15);
          csS[row * 144 + col] = f2fp8(1.0f / (1.0f + __expf(-acc[mi][ni][j])));
        }
    // (d) sigma writes visible before dot-phase reads (lgkm only)
    asm volatile("s_waitcnt lgkmcnt(0)" ::: "memory");
    __builtin_amdgcn_s_barrier();
    __builtin_amdgcn_sched_barrier(0);

    {
      float pc = 0.f, nc = 0.f, pg = 0.f, ng = 0.f;
      const unsigned char* cr = csS + rl * 144;
#pragma unroll
      for (int e = 0; e < 4; ++e) {
        int cb = e * 32 + q * 8;
        uint2 cs8 = *(const uint2*)(cr + cb);
        float sf[8], pf[8];
        CVT8_FP8(sf, cs8)
        CVT8_FP8(pf, pv8[e])
#pragma unroll
        for (int u = 0; u < 8; ++u) {
          float nv = (u < 4) ? (&nv0[e].x)[u] : (&nv1[e].x)[u - 4];
          float wv = WsS[p * 128 + cb + u];
          pc = fmaf(sf[u], pf[u], pc);
          nc = fmaf(sf[u], nv, nc);
          pg = fmaf(wv, pf[u], pg);
          ng = fmaf(wv, nv, ng);
        }
      }
      if (!vld) { pc = 0.f; nc = 0.f; pg = 0.f; ng = 0.f; }
      pc += __shfl_xor(pc, 1); pc += __shfl_xor(pc, 2);
      nc += __shfl_xor(nc, 1); nc += __shfl_xor(nc, 2);
      pg += __shfl_xor(pg, 1); pg += __shfl_xor(pg, 2);
      ng += __shfl_xor(ng, 1); ng += __shfl_xor(ng, 2);
      if (q == 0) {
        pcS[rl] += pc;
        ncS[rl] += nc;
        pgS[rl] += pg;
        ngS[rl] += ng;
      }
    }
    // bottom: dot-phase LDS reads done before next pass's gload16 overwrites BsU8
    asm volatile("s_waitcnt lgkmcnt(0)" ::: "memory");
    __builtin_amdgcn_s_barrier();
    __builtin_amdgcn_sched_barrier(0);
  }
  __syncthreads();
  if (t < 128) {
    int gi2 = i0 + t;
    float contrib = 0.f;
    if (gi2 < NN) {
      float nrm = 1.0f / inv_norm[gi2];  // ||pos||+eps: un-normalization
      float pg = pgS[t] * nrm;
      float pc = pcS[t] * nrm;
      float ng = ngS[t];
      float nc = ncS[t];
      contrib = 0.5f * (softplusf(-pg) + softplusf(ng)) +
                0.5f * (softplusf(-pc) + softplusf(nc));
    }
    contrib = wave_reduce_sum(contrib);
    if (l == 0) atomicAdd(loss_accum, contrib);
  }
}

__global__ void out_kernel(const float* __restrict__ loss_accum, float* __restrict__ out) {
  out[0] = loss_accum[0] * (1.0f / NN);
}

extern "C" void kernel_launch(void* const* d_in, const int* in_sizes, int n_in,
                              void* d_out, int out_size, void* d_ws, size_t ws_size,
                              hipStream_t stream) {
  const float* pos = (const float*)d_in[0];
  const float* neg = (const float*)d_in[1];
  const float* init = (const float*)d_in[2];
  const float* W = (const float*)d_in[3];
  float* out = (float*)d_out;

  char* ws = (char*)d_ws;
  size_t off = 0;
  auto alloc = [&](size_t bytes) {
    void* p = ws + off;
    off = (off + bytes + 255) & ~(size_t)255;
    return p;
  };
  unsigned char* posb8 = (unsigned char*)alloc((size_t)PADN * HH);        // 51.2 MB
  unsigned char* posbT8 = (unsigned char*)alloc((size_t)HH * PADN);       // 51.2 MB
  unsigned char* rbf8 = (unsigned char*)alloc((size_t)PADN * KK);         // 12.8 MB
  unsigned char* rbfT8 = (unsigned char*)alloc((size_t)KK * PADN);        // 12.8 MB
  unsigned char* part8 = (unsigned char*)alloc((size_t)NSPLIT * KK * HH); // 8.4 MB
  float* colpart = (float*)alloc((size_t)PREPB * HH * 4);                 // 2 MB
  float* crblk = (float*)alloc((size_t)NBLK128 * KK * 4);                 // 400 KB
  float* inv_norm = (float*)alloc((size_t)NN * 4);
  unsigned char* mub8 = (unsigned char*)alloc((size_t)KK * HH);
  unsigned char* mubT8 = (unsigned char*)alloc((size_t)KK * HH);
  float* gs = (float*)alloc(HH * 4);
  float* Ws = (float*)alloc(HH * 4);
  float* loss_accum = (float*)alloc(16);

  hipMemsetAsync(loss_accum, 0, sizeof(float), stream);

  prep_kernel<<<PREPB, 256, 0, stream>>>(pos, inv_norm, colpart, posb8);
  transpose_kernel<<<dim3(PADN / 64, HH / 64), 256, 0, stream>>>(posb8, posbT8);
  gs_kernel<<<1, 512, 0, stream>>>(colpart, gs);
  wsum_kernel<<<128, 256, 0, stream>>>(W, gs, Ws);

  norm_mu_kernel<<<KK, 256, 0, stream>>>(init, mub8);
  for (int it = 0; it < ITERS; ++it) {
    dist_mfma<<<NBLK128, 256, 0, stream>>>(posb8, mub8, rbf8, rbfT8, crblk, it == ITERS - 1 ? 1 : 0);
    muup_mfma<<<dim3(4, NSPLIT), 256, 0, stream>>>(rbfT8, posbT8, part8);
    finorm_kernel<<<KK, 256, 0, stream>>>(part8, crblk, mub8, mubT8, it == ITERS - 1 ? 1 : 0);
  }

  loss_mfma<<<NBLK128, 512, 0, stream>>>(rbf8, mubT8, posb8, neg, inv_norm, Ws, loss_accum);
  out_kernel<<<1, 1, 0, stream>>>(loss_accum, out);
}